// Round 6
// baseline (135.094 us; speedup 1.0000x reference)
//
#include <hip/hip_runtime.h>
#include <hip/hip_bf16.h>

#define BATCH 16384
#define BT 8            // batch elements per block
#define NTHREADS 512    // 8 waves

// ---- workspace: bf16 weights, original layout (rows = output neuron, cols = k)
#define W1B_OFF 0                       // [128][64]
#define W2B_OFF (128*64)                // [128][128]
#define W3B_OFF (W2B_OFF + 128*128)     // [512][128]
#define WS_SHORTS (W3B_OFF + 512*128)   // 90112 shorts

// ---- LDS layout (bytes), phase overlays
#define SM_HB    0
#define SM_Z1    2304
#define SM_Z2    6656
#define SM_A2    11008
#define SM_DZ1   0
#define SM_PJ    0
#define SM_T     20224
#define SM_DZ2   20224
#define SM_VT    37632      // bf16 [8][64][8]  Vt[e][n][j] = V_j[n]
#define SM_S1T   45824      // bf16 [128][8]
#define SM_S2T   47872      // bf16 [128][8]
#define SM_SIG   49920      // f32  [8][36]
#define SM_TOTAL 51072

typedef __attribute__((ext_vector_type(8))) short bf16x8;
typedef __attribute__((ext_vector_type(4))) float f32x4;

#define SCHED_FENCE() __builtin_amdgcn_sched_barrier(0)

__device__ __forceinline__ float bf2f(unsigned int u16) {
    unsigned int x = u16 << 16;
    float f; __builtin_memcpy(&f, &x, 4); return f;
}
__device__ __forceinline__ unsigned short f2bf(float f) {
    unsigned int x; __builtin_memcpy(&x, &f, 4);
    x = (x + 0x7FFFu + ((x >> 16) & 1u)) >> 16;
    return (unsigned short)x;
}
__device__ __forceinline__ void unpack8(uint4 q, float* f) {
    f[0] = bf2f(q.x & 0xFFFFu); f[1] = bf2f(q.x >> 16);
    f[2] = bf2f(q.y & 0xFFFFu); f[3] = bf2f(q.y >> 16);
    f[4] = bf2f(q.z & 0xFFFFu); f[5] = bf2f(q.z >> 16);
    f[6] = bf2f(q.w & 0xFFFFu); f[7] = bf2f(q.w >> 16);
}
__device__ __forceinline__ void sp_sig(float x, float& sp, float& sig) {
    float t = __expf(-fabsf(x));
    float r = __builtin_amdgcn_rcpf(1.f + t);
    sig = (x >= 0.f) ? r : 1.f - r;
    sp  = fmaxf(x, 0.f) + __logf(1.f + t);
}
__device__ __forceinline__ float tanh_fast(float x) {
    float t = __expf(-2.f * fabsf(x));
    float y = (1.f - t) * __builtin_amdgcn_rcpf(1.f + t);
    unsigned int xb, yb;
    __builtin_memcpy(&xb, &x, 4);
    __builtin_memcpy(&yb, &y, 4);
    yb |= (xb & 0x80000000u);
    float rr; __builtin_memcpy(&rr, &yb, 4);
    return rr;
}
__device__ __forceinline__ bf16x8 ldfrag(const unsigned short* p) {
    return *reinterpret_cast<const bf16x8*>(p);
}

__global__ void prep_weights(const float* __restrict__ W1,
                             const float* __restrict__ W2,
                             const float* __restrict__ W3,
                             unsigned short* __restrict__ wb) {
    int i = blockIdx.x * blockDim.x + threadIdx.x;
    if (i >= WS_SHORTS) return;
    float v;
    if (i < W2B_OFF) v = W1[i];
    else if (i < W3B_OFF) v = W2[i - W2B_OFF];
    else v = W3[i - W3B_OFF];
    wb[i] = f2bf(v);
}

__global__ __launch_bounds__(NTHREADS, 4)
void logncde_main(const float* __restrict__ hg,
                  const float* __restrict__ sigg,
                  const float* __restrict__ b1,
                  const float* __restrict__ b2,
                  const float* __restrict__ b3,
                  const unsigned short* __restrict__ wsb,
                  float* __restrict__ out) {
    __shared__ __align__(16) char sm[SM_TOTAL];
    unsigned short* hb  = (unsigned short*)(sm + SM_HB);   // [16][72]
    unsigned short* z1b = (unsigned short*)(sm + SM_Z1);   // [16][136]
    unsigned short* z2b = (unsigned short*)(sm + SM_Z2);   // [16][136]
    unsigned short* A2  = (unsigned short*)(sm + SM_A2);   // [64][72]
    unsigned short* s1t = (unsigned short*)(sm + SM_S1T);  // [128][8]
    unsigned short* s2t = (unsigned short*)(sm + SM_S2T);  // [128][8]
    unsigned short* Vt  = (unsigned short*)(sm + SM_VT);   // [8][64][8]
    float*          sigs= (float*)(sm + SM_SIG);           // [8][36]
    unsigned short* Tsm = (unsigned short*)(sm + SM_T);    // [64][72]
    unsigned short* dZ1 = (unsigned short*)(sm + SM_DZ1);  // [64][136]
    unsigned short* dZ2 = (unsigned short*)(sm + SM_DZ2);  // [64][136]
    float*          pj  = (float*)(sm + SM_PJ);            // [8][8][64]

    const int tid = threadIdx.x;
    const int b0 = blockIdx.x * BT;

    const int lane = tid & 63;
    const int w = tid >> 6;
    const int r16 = lane & 15;
    const int kb = lane >> 4;
    const int crow = (lane >> 4) * 4;

    // ---- phase 0: load h + signatures
    {
        int e = tid >> 6, k = tid & 63;
        hb[e * 72 + k] = f2bf(hg[(b0 + e) * 64 + k]);
    }
    if (tid < BT * 36) {
        int e = tid / 36, j = tid % 36;
        sigs[e * 36 + j] = sigg[(b0 + e) * 36 + j];
    }
    __syncthreads();

    // ---- A2 build: A2[m=j*8+e][kidx=e'*8+i] = (e'==e) ? c[i][j]_e : 0
    {
        int e = lane >> 3, kg = lane & 7, j = w;
        uint4 q = {0u, 0u, 0u, 0u};
        if (kg == e) {
            unsigned short c8[8];
            #pragma unroll
            for (int i = 0; i < 8; ++i) {
                float v = 0.f;
                if (i < j) {
                    int p = 7 * i - i * (i - 1) / 2 + (j - i - 1);
                    v = sigs[e * 36 + 8 + p];
                } else if (i > j) {
                    int p = 7 * j - j * (j - 1) / 2 + (i - j - 1);
                    v = -sigs[e * 36 + 8 + p];
                }
                c8[i] = f2bf(v);
            }
            q.x = (unsigned int)c8[0] | ((unsigned int)c8[1] << 16);
            q.y = (unsigned int)c8[2] | ((unsigned int)c8[3] << 16);
            q.z = (unsigned int)c8[4] | ((unsigned int)c8[5] << 16);
            q.w = (unsigned int)c8[6] | ((unsigned int)c8[7] << 16);
        }
        int m = j * 8 + e;
        *reinterpret_cast<uint4*>(&A2[m * 72 + kg * 8]) = q;
    }

    // ---- fwd1 (MFMA): a1[8][128] = h @ W1^T
    {
        const unsigned short* Ab = hb + r16 * 72 + kb * 8;
        const unsigned short* Bb = wsb + W1B_OFF + (w * 16 + r16) * 64 + kb * 8;
        bf16x8 bfr[2], afr[2];
        #pragma unroll
        for (int ks = 0; ks < 2; ++ks) bfr[ks] = ldfrag(Bb + ks * 32);
        #pragma unroll
        for (int ks = 0; ks < 2; ++ks) afr[ks] = ldfrag(Ab + ks * 32);
        SCHED_FENCE();
        f32x4 acc = {};
        #pragma unroll
        for (int ks = 0; ks < 2; ++ks)
            acc = __builtin_amdgcn_mfma_f32_16x16x32_bf16(afr[ks], bfr[ks], acc, 0, 0, 0);
        if (lane < 32) {
            int col = w * 16 + r16;
            float bb = b1[col];
            unsigned short sp4[4];
            #pragma unroll
            for (int rr = 0; rr < 4; ++rr) {
                int e = crow + rr;
                float sp, sg;
                sp_sig(acc[rr] + bb, sp, sg);
                z1b[e * 136 + col] = f2bf(sp);
                sp4[rr] = f2bf(sg);
            }
            uint2 qq;
            qq.x = (unsigned int)sp4[0] | ((unsigned int)sp4[1] << 16);
            qq.y = (unsigned int)sp4[2] | ((unsigned int)sp4[3] << 16);
            *reinterpret_cast<uint2*>(&s1t[col * 8 + crow]) = qq;
        }
    }
    __syncthreads();

    // ---- fwd2 (MFMA): a2 = z1 @ W2^T
    {
        const unsigned short* Ab = z1b + r16 * 136 + kb * 8;
        const unsigned short* Bb = wsb + W2B_OFF + (w * 16 + r16) * 128 + kb * 8;
        bf16x8 bfr[4], afr[4];
        #pragma unroll
        for (int ks = 0; ks < 4; ++ks) bfr[ks] = ldfrag(Bb + ks * 32);
        #pragma unroll
        for (int ks = 0; ks < 4; ++ks) afr[ks] = ldfrag(Ab + ks * 32);
        SCHED_FENCE();
        f32x4 acc = {};
        #pragma unroll
        for (int ks = 0; ks < 4; ++ks)
            acc = __builtin_amdgcn_mfma_f32_16x16x32_bf16(afr[ks], bfr[ks], acc, 0, 0, 0);
        if (lane < 32) {
            int col = w * 16 + r16;
            float bb = b2[col];
            unsigned short sp4[4];
            #pragma unroll
            for (int rr = 0; rr < 4; ++rr) {
                int e = crow + rr;
                float sp, sg;
                sp_sig(acc[rr] + bb, sp, sg);
                z2b[e * 136 + col] = f2bf(sp);
                sp4[rr] = f2bf(sg);
            }
            uint2 qq;
            qq.x = (unsigned int)sp4[0] | ((unsigned int)sp4[1] << 16);
            qq.y = (unsigned int)sp4[2] | ((unsigned int)sp4[3] << 16);
            *reinterpret_cast<uint2*>(&s2t[col * 8 + crow]) = qq;
        }
    }
    __syncthreads();

    // ---- fwd3 (MFMA): V = tanh(z2 @ W3^T + b3)
    {
        const unsigned short* Ab = z2b + r16 * 136 + kb * 8;
        const unsigned short* Bb = wsb + W3B_OFF + kb * 8;
        bf16x8 bfr[16], afr[4];
        #pragma unroll
        for (int nt = 0; nt < 4; ++nt)
            #pragma unroll
            for (int ks = 0; ks < 4; ++ks)
                bfr[nt * 4 + ks] = ldfrag(Bb + (w * 64 + nt * 16 + r16) * 128 + ks * 32);
        #pragma unroll
        for (int ks = 0; ks < 4; ++ks) afr[ks] = ldfrag(Ab + ks * 32);
        SCHED_FENCE();
        f32x4 acc[4] = {};
        #pragma unroll
        for (int nt = 0; nt < 4; ++nt)
            #pragma unroll
            for (int ks = 0; ks < 4; ++ks)
                acc[nt] = __builtin_amdgcn_mfma_f32_16x16x32_bf16(afr[ks], bfr[nt * 4 + ks], acc[nt], 0, 0, 0);
        if (lane < 32) {
            #pragma unroll
            for (int nt = 0; nt < 4; ++nt) {
                int c = w * 64 + nt * 16 + r16;
                float bb = b3[c];
                int n = c & 63;
                #pragma unroll
                for (int rr = 0; rr < 4; ++rr) {
                    int e = crow + rr;
                    Vt[(e * 64 + n) * 8 + w] = f2bf(tanh_fast(acc[nt][rr] + bb));
                }
            }
        }
    }
    __syncthreads();

    // ---- T-build (MFMA): T[64][64] = A2 @ Vt-as-B (all LDS)
    {
        int mt = w & 3, nh = w >> 2;
        const unsigned short* Ab = A2 + (mt * 16 + r16) * 72 + kb * 8;
        bf16x8 afr[2], bfr[2][2];
        #pragma unroll
        for (int ks = 0; ks < 2; ++ks) {
            afr[ks] = ldfrag(Ab + ks * 32);
            int ep = ks * 4 + kb;
            #pragma unroll
            for (int nt = 0; nt < 2; ++nt) {
                int n = nh * 32 + nt * 16 + r16;
                bfr[ks][nt] = ldfrag(&Vt[(ep * 64 + n) * 8]);
            }
        }
        SCHED_FENCE();
        f32x4 acc[2] = {};
        #pragma unroll
        for (int ks = 0; ks < 2; ++ks)
            #pragma unroll
            for (int nt = 0; nt < 2; ++nt)
                acc[nt] = __builtin_amdgcn_mfma_f32_16x16x32_bf16(afr[ks], bfr[ks][nt], acc[nt], 0, 0, 0);
        #pragma unroll
        for (int nt = 0; nt < 2; ++nt) {
            int col = nh * 32 + nt * 16 + r16;
            #pragma unroll
            for (int rr = 0; rr < 4; ++rr) {
                int row = mt * 16 + crow + rr;
                Tsm[row * 72 + col] = f2bf(acc[nt][rr]);
            }
        }
    }
    __syncthreads();

    // ---- jvp1 (MFMA): dA1 = T @ W1^T; mask s1 -> dZ1
    {
        int mt = w & 3, nh = w >> 2;
        const unsigned short* Ab = Tsm + (mt * 16 + r16) * 72 + kb * 8;
        const unsigned short* Bb = wsb + W1B_OFF + kb * 8;
        bf16x8 bfr[8], afr[2];
        #pragma unroll
        for (int nt = 0; nt < 4; ++nt)
            #pragma unroll
            for (int ks = 0; ks < 2; ++ks)
                bfr[nt * 2 + ks] = ldfrag(Bb + (nh * 64 + nt * 16 + r16) * 64 + ks * 32);
        #pragma unroll
        for (int ks = 0; ks < 2; ++ks) afr[ks] = ldfrag(Ab + ks * 32);
        SCHED_FENCE();
        f32x4 acc[4] = {};
        #pragma unroll
        for (int nt = 0; nt < 4; ++nt)
            #pragma unroll
            for (int ks = 0; ks < 2; ++ks)
                acc[nt] = __builtin_amdgcn_mfma_f32_16x16x32_bf16(afr[ks], bfr[nt * 2 + ks], acc[nt], 0, 0, 0);
        int ebase = crow & 7;
        #pragma unroll
        for (int nt = 0; nt < 4; ++nt) {
            int col = nh * 64 + nt * 16 + r16;
            uint2 qq = *reinterpret_cast<const uint2*>(&s1t[col * 8 + ebase]);
            float s4[4];
            s4[0] = bf2f(qq.x & 0xFFFFu); s4[1] = bf2f(qq.x >> 16);
            s4[2] = bf2f(qq.y & 0xFFFFu); s4[3] = bf2f(qq.y >> 16);
            #pragma unroll
            for (int rr = 0; rr < 4; ++rr) {
                int row = mt * 16 + crow + rr;
                dZ1[row * 136 + col] = f2bf(acc[nt][rr] * s4[rr]);
            }
        }
    }
    __syncthreads();

    // ---- jvp2 (MFMA): dA2 = dZ1 @ W2^T; mask s2 -> dZ2
    {
        int mt = w & 3, nh = w >> 2;
        const unsigned short* Ab = dZ1 + (mt * 16 + r16) * 136 + kb * 8;
        const unsigned short* Bb = wsb + W2B_OFF + kb * 8;
        bf16x8 bfr[16], afr[4];
        #pragma unroll
        for (int nt = 0; nt < 4; ++nt)
            #pragma unroll
            for (int ks = 0; ks < 4; ++ks)
                bfr[nt * 4 + ks] = ldfrag(Bb + (nh * 64 + nt * 16 + r16) * 128 + ks * 32);
        #pragma unroll
        for (int ks = 0; ks < 4; ++ks) afr[ks] = ldfrag(Ab + ks * 32);
        SCHED_FENCE();
        f32x4 acc[4] = {};
        #pragma unroll
        for (int nt = 0; nt < 4; ++nt)
            #pragma unroll
            for (int ks = 0; ks < 4; ++ks)
                acc[nt] = __builtin_amdgcn_mfma_f32_16x16x32_bf16(afr[ks], bfr[nt * 4 + ks], acc[nt], 0, 0, 0);
        int ebase = crow & 7;
        #pragma unroll
        for (int nt = 0; nt < 4; ++nt) {
            int col = nh * 64 + nt * 16 + r16;
            uint2 qq = *reinterpret_cast<const uint2*>(&s2t[col * 8 + ebase]);
            float s4[4];
            s4[0] = bf2f(qq.x & 0xFFFFu); s4[1] = bf2f(qq.x >> 16);
            s4[2] = bf2f(qq.y & 0xFFFFu); s4[3] = bf2f(qq.y >> 16);
            #pragma unroll
            for (int rr = 0; rr < 4; ++rr) {
                int row = mt * 16 + crow + rr;
                dZ2[row * 136 + col] = f2bf(acc[nt][rr] * s4[rr]);
            }
        }
    }
    __syncthreads();

    // ---- jvp3 (MFMA): wave w = field j; mask tanh' -> pj
    {
        int j = w;
        int mt = j >> 1, half = j & 1;
        const unsigned short* Ab = dZ2 + (mt * 16 + r16) * 136 + kb * 8;
        const unsigned short* Bb = wsb + W3B_OFF + (j * 64) * 128 + kb * 8;
        bf16x8 bfr[16], afr[4];
        #pragma unroll
        for (int nt = 0; nt < 4; ++nt)
            #pragma unroll
            for (int ks = 0; ks < 4; ++ks)
                bfr[nt * 4 + ks] = ldfrag(Bb + (nt * 16 + r16) * 128 + ks * 32);
        #pragma unroll
        for (int ks = 0; ks < 4; ++ks) afr[ks] = ldfrag(Ab + ks * 32);
        SCHED_FENCE();
        f32x4 acc[4] = {};
        #pragma unroll
        for (int nt = 0; nt < 4; ++nt)
            #pragma unroll
            for (int ks = 0; ks < 4; ++ks)
                acc[nt] = __builtin_amdgcn_mfma_f32_16x16x32_bf16(afr[ks], bfr[nt * 4 + ks], acc[nt], 0, 0, 0);
        if ((crow >> 3) == half) {
            #pragma unroll
            for (int nt = 0; nt < 4; ++nt) {
                int np = nt * 16 + r16;
                #pragma unroll
                for (int rr = 0; rr < 4; ++rr) {
                    int e = (crow + rr) & 7;
                    float v = bf2f(Vt[(e * 64 + np) * 8 + j]);
                    pj[(j * 8 + e) * 64 + np] = (1.f - v * v) * acc[nt][rr];
                }
            }
        }
    }
    __syncthreads();

    // ---- reduce
    {
        int e = tid >> 6, np = tid & 63;
        uint4 q = *reinterpret_cast<const uint4*>(&Vt[(e * 64 + np) * 8]);
        float v8[8]; unpack8(q, v8);
        float s = 0.f;
        #pragma unroll
        for (int j = 0; j < 8; ++j) s += pj[(j * 8 + e) * 64 + np];
        float l1 = 0.f;
        #pragma unroll
        for (int i = 0; i < 8; ++i) l1 += sigs[e * 36 + i] * v8[i];
        out[(b0 + e) * 64 + np] = l1 + s;
    }
}

extern "C" void kernel_launch(void* const* d_in, const int* in_sizes, int n_in,
                              void* d_out, int out_size, void* d_ws, size_t ws_size,
                              hipStream_t stream) {
    const float* hg  = (const float*)d_in[0];
    const float* sg  = (const float*)d_in[1];
    const float* W1  = (const float*)d_in[2];
    const float* b1  = (const float*)d_in[3];
    const float* W2  = (const float*)d_in[4];
    const float* b2  = (const float*)d_in[5];
    const float* W3  = (const float*)d_in[6];
    const float* b3  = (const float*)d_in[7];
    float* outp = (float*)d_out;
    unsigned short* wsb = (unsigned short*)d_ws;

    hipLaunchKernelGGL(prep_weights, dim3((WS_SHORTS + 255) / 256), dim3(256), 0, stream,
                       W1, W2, W3, wsb);
    hipLaunchKernelGGL(logncde_main, dim3(BATCH / BT), dim3(NTHREADS), 0, stream,
                       hg, sg, b1, b2, b3, wsb, outp);
}

// Round 7
// 99.319 us; speedup vs baseline: 1.3602x; 1.3602x over previous
//
#include <hip/hip_runtime.h>
#include <hip/hip_bf16.h>

#define NEL 16384

// ---- workspace layout (offsets in SHORTS from d_ws base) ----
#define W1B_OFF 0                         // bf16 W1 [128][64]
#define W2B_OFF 8192                      // bf16 W2 [128][128]
#define W3B_OFF 24576                     // bf16 W3 [512][128]
#define WS_WEIGHTS 90112
#define S1_OFF  90112                     // bf16 [NEL][128]
#define S2_OFF  (S1_OFF + NEL*128)
#define Z2_OFF  (S2_OFF + NEL*128)
#define V_OFF   (Z2_OFF + NEL*128)        // bf16 [NEL][512]
#define DZ2_OFF (V_OFF + NEL*512)         // bf16 [NEL][8][128]

typedef __attribute__((ext_vector_type(8))) short bf16x8;
typedef __attribute__((ext_vector_type(4))) float f32x4;

__device__ __forceinline__ float bf2f(unsigned int u16) {
    unsigned int x = u16 << 16;
    float f; __builtin_memcpy(&f, &x, 4); return f;
}
__device__ __forceinline__ unsigned short f2bf(float f) {
    unsigned int x; __builtin_memcpy(&x, &f, 4);
    x = (x + 0x7FFFu + ((x >> 16) & 1u)) >> 16;
    return (unsigned short)x;
}
__device__ __forceinline__ void sp_sig(float x, float& sp, float& sig) {
    float t = __expf(-fabsf(x));
    float r = __builtin_amdgcn_rcpf(1.f + t);
    sig = (x >= 0.f) ? r : 1.f - r;
    sp  = fmaxf(x, 0.f) + __logf(1.f + t);
}
__device__ __forceinline__ float tanh_fast(float x) {
    float t = __expf(-2.f * fabsf(x));
    float y = (1.f - t) * __builtin_amdgcn_rcpf(1.f + t);
    unsigned int xb, yb;
    __builtin_memcpy(&xb, &x, 4);
    __builtin_memcpy(&yb, &y, 4);
    yb |= (xb & 0x80000000u);
    float rr; __builtin_memcpy(&rr, &yb, 4);
    return rr;
}
__device__ __forceinline__ bf16x8 ldfrag(const unsigned short* p) {
    return *reinterpret_cast<const bf16x8*>(p);
}
__device__ __forceinline__ void cpu4(unsigned short* dst, const unsigned short* src) {
    *reinterpret_cast<uint4*>(dst) = *reinterpret_cast<const uint4*>(src);
}

// ---- prep: bf16 copies of W1, W2, W3 in [out][k] layout ----
__global__ void prep_weights(const float* __restrict__ W1,
                             const float* __restrict__ W2,
                             const float* __restrict__ W3,
                             unsigned short* __restrict__ wb) {
    int i = blockIdx.x * blockDim.x + threadIdx.x;
    if (i >= WS_WEIGHTS) return;
    float v;
    if (i < W2B_OFF) v = W1[i];
    else if (i < W3B_OFF) v = W2[i - W2B_OFF];
    else v = W3[i - W3B_OFF];
    wb[i] = f2bf(v);
}

// ============ K1: fwd1 + fwd2 (Z1 stays in LDS) ============
// grid 256 blocks x 256 thr; block = 64 elements.
// LDS: phase1 W1s[128][72]@0, Hs[64][72]@18432; phase2 W2s[128][136]@0; Z1s[64][136]@34816
#define K1_LDS 52224
__global__ __launch_bounds__(256, 2)
void k1_fwd12(const float* __restrict__ hg,
              const float* __restrict__ b1,
              const float* __restrict__ b2,
              unsigned short* __restrict__ wsb) {
    __shared__ __align__(16) char sm[K1_LDS];
    unsigned short* w1s = (unsigned short*)(sm);            // [128][72]
    unsigned short* hs  = (unsigned short*)(sm + 18432);    // [64][72]
    unsigned short* w2s = (unsigned short*)(sm);            // [128][136] (phase2)
    unsigned short* z1s = (unsigned short*)(sm + 34816);    // [64][136]
    unsigned short* S1g = wsb + S1_OFF;
    unsigned short* S2g = wsb + S2_OFF;
    unsigned short* Z2g = wsb + Z2_OFF;

    const int tid = threadIdx.x;
    const int e0 = blockIdx.x * 64;
    const int lane = tid & 63;
    const int w = tid >> 6;            // wave 0..3 = m-tile
    const int r16 = lane & 15;
    const int kb = lane >> 4;

    // stage W1s (1024 uint4) + Hs (4096 scalars, fp32->bf16)
    #pragma unroll
    for (int q = 0; q < 4; ++q) {
        int idx = q * 256 + tid;            // 0..1023
        int row = idx >> 3, u4 = idx & 7;
        cpu4(&w1s[row * 72 + u4 * 8], &wsb[W1B_OFF + row * 64 + u4 * 8]);
    }
    #pragma unroll
    for (int q = 0; q < 16; ++q) {
        int idx = q * 256 + tid;            // 0..4095
        int row = idx >> 6, k = idx & 63;
        hs[row * 72 + k] = f2bf(hg[(e0 + row) * 64 + k]);
    }
    __syncthreads();

    // fwd1: M=64 N=128 K=64
    {
        const unsigned short* Ab = hs + (w * 16 + r16) * 72 + kb * 8;
        bf16x8 a0 = ldfrag(Ab), a1 = ldfrag(Ab + 32);
        f32x4 acc[8] = {};
        #pragma unroll
        for (int nt = 0; nt < 8; ++nt) {
            const unsigned short* Bb = w1s + (nt * 16 + r16) * 72 + kb * 8;
            acc[nt] = __builtin_amdgcn_mfma_f32_16x16x32_bf16(a0, ldfrag(Bb), acc[nt], 0, 0, 0);
            acc[nt] = __builtin_amdgcn_mfma_f32_16x16x32_bf16(a1, ldfrag(Bb + 32), acc[nt], 0, 0, 0);
        }
        int rbase = w * 16 + kb * 4;
        #pragma unroll
        for (int nt = 0; nt < 8; ++nt) {
            int col = nt * 16 + r16;
            float bb = b1[col];
            #pragma unroll
            for (int rr = 0; rr < 4; ++rr) {
                float sp, sg;
                sp_sig(acc[nt][rr] + bb, sp, sg);
                z1s[(rbase + rr) * 136 + col] = f2bf(sp);
                S1g[(e0 + rbase + rr) * 128 + col] = f2bf(sg);
            }
        }
    }
    __syncthreads();

    // stage W2s (2048 uint4) over W1s/Hs
    #pragma unroll
    for (int q = 0; q < 8; ++q) {
        int idx = q * 256 + tid;            // 0..2047
        int row = idx >> 4, u4 = idx & 15;
        cpu4(&w2s[row * 136 + u4 * 8], &wsb[W2B_OFF + row * 128 + u4 * 8]);
    }
    __syncthreads();

    // fwd2: M=64 N=128 K=128
    {
        const unsigned short* Ab = z1s + (w * 16 + r16) * 136 + kb * 8;
        bf16x8 a[4];
        #pragma unroll
        for (int ks = 0; ks < 4; ++ks) a[ks] = ldfrag(Ab + ks * 32);
        f32x4 acc[8] = {};
        #pragma unroll
        for (int nt = 0; nt < 8; ++nt) {
            const unsigned short* Bb = w2s + (nt * 16 + r16) * 136 + kb * 8;
            #pragma unroll
            for (int ks = 0; ks < 4; ++ks)
                acc[nt] = __builtin_amdgcn_mfma_f32_16x16x32_bf16(a[ks], ldfrag(Bb + ks * 32), acc[nt], 0, 0, 0);
        }
        int rbase = w * 16 + kb * 4;
        #pragma unroll
        for (int nt = 0; nt < 8; ++nt) {
            int col = nt * 16 + r16;
            float bb = b2[col];
            #pragma unroll
            for (int rr = 0; rr < 4; ++rr) {
                float sp, sg;
                sp_sig(acc[nt][rr] + bb, sp, sg);
                Z2g[(e0 + rbase + rr) * 128 + col] = f2bf(sp);
                S2g[(e0 + rbase + rr) * 128 + col] = f2bf(sg);
            }
        }
    }
}

// ============ K2: fwd3 (V = tanh(Z2 @ W3^T + b3)) ============
// grid 256 x 256 thr; block = 64 elements, N=512 in 4 chunks of 128.
// LDS: Z2s[64][136]@0 (17408), Wc[128][136]@17408 (34816) -> 52224
#define K2_LDS 52224
__global__ __launch_bounds__(256, 2)
void k2_fwd3(const float* __restrict__ b3,
             unsigned short* __restrict__ wsb) {
    __shared__ __align__(16) char sm[K2_LDS];
    unsigned short* z2s = (unsigned short*)(sm);            // [64][136]
    unsigned short* wc  = (unsigned short*)(sm + 17408);    // [128][136]
    const unsigned short* Z2g = wsb + Z2_OFF;
    unsigned short* Vg = wsb + V_OFF;

    const int tid = threadIdx.x;
    const int e0 = blockIdx.x * 64;
    const int lane = tid & 63;
    const int w = tid >> 6;
    const int r16 = lane & 15;
    const int kb = lane >> 4;

    // stage Z2s (1024 uint4)
    #pragma unroll
    for (int q = 0; q < 4; ++q) {
        int idx = q * 256 + tid;
        int row = idx >> 4, u4 = idx & 15;
        cpu4(&z2s[row * 136 + u4 * 8], const_cast<unsigned short*>(&Z2g[(e0 + row) * 128 + u4 * 8]));
    }

    for (int nc = 0; nc < 4; ++nc) {
        __syncthreads();   // protect wc from previous iteration's readers
        // stage Wc rows = W3[nc*128 .. +128)
        #pragma unroll
        for (int q = 0; q < 8; ++q) {
            int idx = q * 256 + tid;
            int row = idx >> 4, u4 = idx & 15;
            cpu4(&wc[row * 136 + u4 * 8], &wsb[W3B_OFF + (nc * 128 + row) * 128 + u4 * 8]);
        }
        __syncthreads();

        const unsigned short* Ab = z2s + (w * 16 + r16) * 136 + kb * 8;
        bf16x8 a[4];
        #pragma unroll
        for (int ks = 0; ks < 4; ++ks) a[ks] = ldfrag(Ab + ks * 32);
        f32x4 acc[8] = {};
        #pragma unroll
        for (int nt = 0; nt < 8; ++nt) {
            const unsigned short* Bb = wc + (nt * 16 + r16) * 136 + kb * 8;
            #pragma unroll
            for (int ks = 0; ks < 4; ++ks)
                acc[nt] = __builtin_amdgcn_mfma_f32_16x16x32_bf16(a[ks], ldfrag(Bb + ks * 32), acc[nt], 0, 0, 0);
        }
        int rbase = w * 16 + kb * 4;
        #pragma unroll
        for (int nt = 0; nt < 8; ++nt) {
            int c = nc * 128 + nt * 16 + r16;
            float bb = b3[c];
            #pragma unroll
            for (int rr = 0; rr < 4; ++rr) {
                float v = tanh_fast(acc[nt][rr] + bb);
                Vg[(e0 + rbase + rr) * 512 + c] = f2bf(v);
            }
        }
    }
}

// ============ K3: T-build + jvp1 + jvp2 ============
// grid 2048 x 256 thr; block = 8 elements -> 64 rows m = e_loc*8 + j.
// LDS: W[0..34816) = W1s[128][72] then W2s[128][136];
//      Ts[64][72]@34816 (9216); dZ1s[64][136]@44032 (17408, Vs[8][520] overlays head);
//      sigs[288]f32@61440 (1152) -> 62592
#define K3_LDS 62592
__global__ __launch_bounds__(256, 2)
void k3_jvp12(const float* __restrict__ sigg,
              unsigned short* __restrict__ wsb) {
    __shared__ __align__(16) char sm[K3_LDS];
    unsigned short* w1s  = (unsigned short*)(sm);            // [128][72]
    unsigned short* w2s  = (unsigned short*)(sm);            // [128][136] (later)
    unsigned short* ts   = (unsigned short*)(sm + 34816);    // [64][72]
    unsigned short* dz1s = (unsigned short*)(sm + 44032);    // [64][136]
    unsigned short* vs   = (unsigned short*)(sm + 44032);    // [8][520] (dead before dz1s writes)
    float*          sigsm= (float*)(sm + 61440);             // [288]
    const unsigned short* S1g = wsb + S1_OFF;
    const unsigned short* S2g = wsb + S2_OFF;
    const unsigned short* Vg  = wsb + V_OFF;
    unsigned short* DZ2g = wsb + DZ2_OFF;

    const int tid = threadIdx.x;
    const int e0 = blockIdx.x * 8;
    const int lane = tid & 63;
    const int w = tid >> 6;
    const int r16 = lane & 15;
    const int kb = lane >> 4;

    // stage Vs (512 uint4), W1s (1024 uint4), sigs (288 f32)
    #pragma unroll
    for (int q = 0; q < 2; ++q) {
        int idx = q * 256 + tid;               // 0..511
        int row = idx >> 6, u4 = idx & 63;
        cpu4(&vs[row * 520 + u4 * 8], const_cast<unsigned short*>(&Vg[(e0 + row) * 512 + u4 * 8]));
    }
    #pragma unroll
    for (int q = 0; q < 4; ++q) {
        int idx = q * 256 + tid;
        int row = idx >> 3, u4 = idx & 7;
        cpu4(&w1s[row * 72 + u4 * 8], &wsb[W1B_OFF + row * 64 + u4 * 8]);
    }
    #pragma unroll
    for (int q = 0; q < 2; ++q) {
        int idx = q * 256 + tid;
        if (idx < 288) sigsm[idx] = sigg[e0 * 36 + idx];
    }
    __syncthreads();

    // T-build: T[m=e*8+j][k] = sum_i c[i][j]_e * V[e][i*64+k]
    {
        int m = tid >> 2, kq = tid & 3;
        int e = m >> 3, j = m & 7;
        float c8[8];
        #pragma unroll
        for (int i = 0; i < 8; ++i) {
            float v = 0.f;
            if (i < j) {
                int p = 7 * i - i * (i - 1) / 2 + (j - i - 1);
                v = sigsm[e * 36 + 8 + p];
            } else if (i > j) {
                int p = 7 * j - j * (j - 1) / 2 + (i - j - 1);
                v = -sigsm[e * 36 + 8 + p];
            }
            c8[i] = v;
        }
        #pragma unroll
        for (int kk = 0; kk < 16; ++kk) {
            int k = kq * 16 + kk;
            float s = 0.f;
            #pragma unroll
            for (int i = 0; i < 8; ++i) s += c8[i] * bf2f(vs[e * 520 + i * 64 + k]);
            ts[m * 72 + k] = f2bf(s);
        }
    }
    __syncthreads();

    // jvp1: dZ1 = (T @ W1^T) .* s1[e]   M=64 N=128 K=64
    {
        const unsigned short* Ab = ts + (w * 16 + r16) * 72 + kb * 8;
        bf16x8 a0 = ldfrag(Ab), a1 = ldfrag(Ab + 32);
        f32x4 acc[8] = {};
        #pragma unroll
        for (int nt = 0; nt < 8; ++nt) {
            const unsigned short* Bb = w1s + (nt * 16 + r16) * 72 + kb * 8;
            acc[nt] = __builtin_amdgcn_mfma_f32_16x16x32_bf16(a0, ldfrag(Bb), acc[nt], 0, 0, 0);
            acc[nt] = __builtin_amdgcn_mfma_f32_16x16x32_bf16(a1, ldfrag(Bb + 32), acc[nt], 0, 0, 0);
        }
        int rbase = w * 16 + kb * 4;
        int e_loc = rbase >> 3;                 // constant over rr (rbase&7 in {0,4})
        #pragma unroll
        for (int nt = 0; nt < 8; ++nt) {
            int col = nt * 16 + r16;
            float s1v = bf2f(S1g[(e0 + e_loc) * 128 + col]);
            #pragma unroll
            for (int rr = 0; rr < 4; ++rr)
                dz1s[(rbase + rr) * 136 + col] = f2bf(acc[nt][rr] * s1v);
        }
    }
    __syncthreads();

    // stage W2s over W1s
    #pragma unroll
    for (int q = 0; q < 8; ++q) {
        int idx = q * 256 + tid;
        int row = idx >> 4, u4 = idx & 15;
        cpu4(&w2s[row * 136 + u4 * 8], &wsb[W2B_OFF + row * 128 + u4 * 8]);
    }
    __syncthreads();

    // jvp2: dZ2 = (dZ1 @ W2^T) .* s2[e]  -> global [e][j][128]
    {
        const unsigned short* Ab = dz1s + (w * 16 + r16) * 136 + kb * 8;
        bf16x8 a[4];
        #pragma unroll
        for (int ks = 0; ks < 4; ++ks) a[ks] = ldfrag(Ab + ks * 32);
        f32x4 acc[8] = {};
        #pragma unroll
        for (int nt = 0; nt < 8; ++nt) {
            const unsigned short* Bb = w2s + (nt * 16 + r16) * 136 + kb * 8;
            #pragma unroll
            for (int ks = 0; ks < 4; ++ks)
                acc[nt] = __builtin_amdgcn_mfma_f32_16x16x32_bf16(a[ks], ldfrag(Bb + ks * 32), acc[nt], 0, 0, 0);
        }
        int rbase = w * 16 + kb * 4;
        int e_loc = rbase >> 3;
        int jbase = rbase & 7;
        #pragma unroll
        for (int nt = 0; nt < 8; ++nt) {
            int col = nt * 16 + r16;
            float s2v = bf2f(S2g[(e0 + e_loc) * 128 + col]);
            #pragma unroll
            for (int rr = 0; rr < 4; ++rr)
                DZ2g[((e0 + e_loc) * 8 + jbase + rr) * 128 + col] = f2bf(acc[nt][rr] * s2v);
        }
    }
}

// ============ K4: jvp3 + mask + level-1, atomic accumulate ============
// grid (256, 8): blockIdx.x = 64-element tile, blockIdx.y = field j.
// LDS: Adz[64][136]@0, W3j[64][136]@17408 -> 34816
#define K4_LDS 34816
__global__ __launch_bounds__(256, 4)
void k4_jvp3(const float* __restrict__ sigg,
             const unsigned short* __restrict__ wsb,
             float* __restrict__ out) {
    __shared__ __align__(16) char sm[K4_LDS];
    unsigned short* adz = (unsigned short*)(sm);            // [64][136]
    unsigned short* w3j = (unsigned short*)(sm + 17408);    // [64][136]
    const unsigned short* Vg = wsb + V_OFF;
    const unsigned short* DZ2g = wsb + DZ2_OFF;

    const int tid = threadIdx.x;
    const int e0 = blockIdx.x * 64;
    const int j = blockIdx.y;
    const int lane = tid & 63;
    const int w = tid >> 6;
    const int r16 = lane & 15;
    const int kb = lane >> 4;

    // stage A = dZ2[(e, j)] rows, and B = W3 rows j*64..+64 (each 1024 uint4)
    #pragma unroll
    for (int q = 0; q < 4; ++q) {
        int idx = q * 256 + tid;
        int row = idx >> 4, u4 = idx & 15;
        cpu4(&adz[row * 136 + u4 * 8], const_cast<unsigned short*>(&DZ2g[((e0 + row) * 8 + j) * 128 + u4 * 8]));
        cpu4(&w3j[row * 136 + u4 * 8], const_cast<unsigned short*>(&wsb[W3B_OFF + (j * 64 + row) * 128 + u4 * 8]));
    }
    __syncthreads();

    // GEMM M=64 N=64 K=128
    const unsigned short* Ab = adz + (w * 16 + r16) * 136 + kb * 8;
    bf16x8 a[4];
    #pragma unroll
    for (int ks = 0; ks < 4; ++ks) a[ks] = ldfrag(Ab + ks * 32);
    f32x4 acc[4] = {};
    #pragma unroll
    for (int nt = 0; nt < 4; ++nt) {
        const unsigned short* Bb = w3j + (nt * 16 + r16) * 136 + kb * 8;
        #pragma unroll
        for (int ks = 0; ks < 4; ++ks)
            acc[nt] = __builtin_amdgcn_mfma_f32_16x16x32_bf16(a[ks], ldfrag(Bb + ks * 32), acc[nt], 0, 0, 0);
    }

    // epilogue: out[e][n'] += sig1_j*V[e][j*64+n'] + (1-V^2)*dA3
    int rbase = w * 16 + kb * 4;
    float sigv[4];
    #pragma unroll
    for (int rr = 0; rr < 4; ++rr)
        sigv[rr] = sigg[(e0 + rbase + rr) * 36 + j];
    #pragma unroll
    for (int nt = 0; nt < 4; ++nt) {
        int np = nt * 16 + r16;
        #pragma unroll
        for (int rr = 0; rr < 4; ++rr) {
            int e = e0 + rbase + rr;
            float v = bf2f(Vg[e * 512 + j * 64 + np]);
            float val = sigv[rr] * v + (1.f - v * v) * acc[nt][rr];
            atomicAdd(&out[e * 64 + np], val);
        }
    }
}

extern "C" void kernel_launch(void* const* d_in, const int* in_sizes, int n_in,
                              void* d_out, int out_size, void* d_ws, size_t ws_size,
                              hipStream_t stream) {
    const float* hg  = (const float*)d_in[0];
    const float* sg  = (const float*)d_in[1];
    const float* W1  = (const float*)d_in[2];
    const float* b1  = (const float*)d_in[3];
    const float* W2  = (const float*)d_in[4];
    const float* b2  = (const float*)d_in[5];
    const float* W3  = (const float*)d_in[6];
    const float* b3  = (const float*)d_in[7];
    float* outp = (float*)d_out;
    unsigned short* wsb = (unsigned short*)d_ws;

    hipMemsetAsync(d_out, 0, (size_t)NEL * 64 * sizeof(float), stream);
    hipLaunchKernelGGL(prep_weights, dim3((WS_WEIGHTS + 255) / 256), dim3(256), 0, stream,
                       W1, W2, W3, wsb);
    hipLaunchKernelGGL(k1_fwd12, dim3(NEL / 64), dim3(256), 0, stream, hg, b1, b2, wsb);
    hipLaunchKernelGGL(k2_fwd3,  dim3(NEL / 64), dim3(256), 0, stream, b3, wsb);
    hipLaunchKernelGGL(k3_jvp12, dim3(NEL / 8),  dim3(256), 0, stream, sg, wsb);
    hipLaunchKernelGGL(k4_jvp3,  dim3(NEL / 64, 8), dim3(256), 0, stream, sg, wsb, outp);
}

// Round 8
// 82.776 us; speedup vs baseline: 1.6320x; 1.1998x over previous
//
#include <hip/hip_runtime.h>
#include <hip/hip_bf16.h>

#define NEL 16384

// ---- workspace layout (offsets in SHORTS from d_ws base) ----
#define W1B_OFF 0                         // bf16 W1 [128][64]
#define W2B_OFF 8192                      // bf16 W2 [128][128]
#define W3B_OFF 24576                     // bf16 W3 [512][128]
#define WS_WEIGHTS 90112
#define S1_OFF  90112                     // bf16 [NEL][128]
#define S2_OFF  (S1_OFF + NEL*128)
#define Z2_OFF  (S2_OFF + NEL*128)
#define V_OFF   (Z2_OFF + NEL*128)        // bf16 [NEL][512]
#define DZ1_OFF (V_OFF + NEL*512)         // bf16 [NEL*8][128]  (row m = e*8+j)
#define DZ2_OFF (DZ1_OFF + NEL*8*128)     // bf16 [NEL*8][128]

typedef __attribute__((ext_vector_type(8))) short bf16x8;
typedef __attribute__((ext_vector_type(4))) float f32x4;

__device__ __forceinline__ float bf2f(unsigned int u16) {
    unsigned int x = u16 << 16;
    float f; __builtin_memcpy(&f, &x, 4); return f;
}
__device__ __forceinline__ unsigned short f2bf(float f) {
    unsigned int x; __builtin_memcpy(&x, &f, 4);
    x = (x + 0x7FFFu + ((x >> 16) & 1u)) >> 16;
    return (unsigned short)x;
}
__device__ __forceinline__ void unpack8(uint4 q, float* f) {
    f[0] = bf2f(q.x & 0xFFFFu); f[1] = bf2f(q.x >> 16);
    f[2] = bf2f(q.y & 0xFFFFu); f[3] = bf2f(q.y >> 16);
    f[4] = bf2f(q.z & 0xFFFFu); f[5] = bf2f(q.z >> 16);
    f[6] = bf2f(q.w & 0xFFFFu); f[7] = bf2f(q.w >> 16);
}
__device__ __forceinline__ void sp_sig(float x, float& sp, float& sig) {
    float t = __expf(-fabsf(x));
    float r = __builtin_amdgcn_rcpf(1.f + t);
    sig = (x >= 0.f) ? r : 1.f - r;
    sp  = fmaxf(x, 0.f) + __logf(1.f + t);
}
__device__ __forceinline__ float tanh_fast(float x) {
    float t = __expf(-2.f * fabsf(x));
    float y = (1.f - t) * __builtin_amdgcn_rcpf(1.f + t);
    unsigned int xb, yb;
    __builtin_memcpy(&xb, &x, 4);
    __builtin_memcpy(&yb, &y, 4);
    yb |= (xb & 0x80000000u);
    float rr; __builtin_memcpy(&rr, &yb, 4);
    return rr;
}
__device__ __forceinline__ bf16x8 ldfrag(const unsigned short* p) {
    return *reinterpret_cast<const bf16x8*>(p);
}
__device__ __forceinline__ void cpu4(unsigned short* dst, const unsigned short* src) {
    *reinterpret_cast<uint4*>(dst) = *reinterpret_cast<const uint4*>(src);
}

// ---- prep: bf16 copies of W1, W2, W3 in [out][k] layout ----
__global__ void prep_weights(const float* __restrict__ W1,
                             const float* __restrict__ W2,
                             const float* __restrict__ W3,
                             unsigned short* __restrict__ wb) {
    int i = blockIdx.x * blockDim.x + threadIdx.x;
    if (i >= WS_WEIGHTS) return;
    float v;
    if (i < W2B_OFF) v = W1[i];
    else if (i < W3B_OFF) v = W2[i - W2B_OFF];
    else v = W3[i - W3B_OFF];
    wb[i] = f2bf(v);
}

// ============ K1: fwd1 + fwd2 (Z1 stays in LDS) ============
#define K1_LDS 52224
__global__ __launch_bounds__(256, 2)
void k1_fwd12(const float* __restrict__ hg,
              const float* __restrict__ b1,
              const float* __restrict__ b2,
              unsigned short* __restrict__ wsb) {
    __shared__ __align__(16) char sm[K1_LDS];
    unsigned short* w1s = (unsigned short*)(sm);            // [128][72]
    unsigned short* hs  = (unsigned short*)(sm + 18432);    // [64][72]
    unsigned short* w2s = (unsigned short*)(sm);            // [128][136] (phase2)
    unsigned short* z1s = (unsigned short*)(sm + 34816);    // [64][136]
    unsigned short* S1g = wsb + S1_OFF;
    unsigned short* S2g = wsb + S2_OFF;
    unsigned short* Z2g = wsb + Z2_OFF;

    const int tid = threadIdx.x;
    const int e0 = blockIdx.x * 64;
    const int lane = tid & 63;
    const int w = tid >> 6;
    const int r16 = lane & 15;
    const int kb = lane >> 4;

    #pragma unroll
    for (int q = 0; q < 4; ++q) {
        int idx = q * 256 + tid;
        int row = idx >> 3, u4 = idx & 7;
        cpu4(&w1s[row * 72 + u4 * 8], &wsb[W1B_OFF + row * 64 + u4 * 8]);
    }
    #pragma unroll
    for (int q = 0; q < 16; ++q) {
        int idx = q * 256 + tid;
        int row = idx >> 6, k = idx & 63;
        hs[row * 72 + k] = f2bf(hg[(e0 + row) * 64 + k]);
    }
    __syncthreads();

    // fwd1: M=64 N=128 K=64
    {
        const unsigned short* Ab = hs + (w * 16 + r16) * 72 + kb * 8;
        bf16x8 a0 = ldfrag(Ab), a1 = ldfrag(Ab + 32);
        f32x4 acc[8] = {};
        #pragma unroll
        for (int nt = 0; nt < 8; ++nt) {
            const unsigned short* Bb = w1s + (nt * 16 + r16) * 72 + kb * 8;
            acc[nt] = __builtin_amdgcn_mfma_f32_16x16x32_bf16(a0, ldfrag(Bb), acc[nt], 0, 0, 0);
            acc[nt] = __builtin_amdgcn_mfma_f32_16x16x32_bf16(a1, ldfrag(Bb + 32), acc[nt], 0, 0, 0);
        }
        int rbase = w * 16 + kb * 4;
        #pragma unroll
        for (int nt = 0; nt < 8; ++nt) {
            int col = nt * 16 + r16;
            float bb = b1[col];
            #pragma unroll
            for (int rr = 0; rr < 4; ++rr) {
                float sp, sg;
                sp_sig(acc[nt][rr] + bb, sp, sg);
                z1s[(rbase + rr) * 136 + col] = f2bf(sp);
                S1g[(e0 + rbase + rr) * 128 + col] = f2bf(sg);
            }
        }
    }
    __syncthreads();

    #pragma unroll
    for (int q = 0; q < 8; ++q) {
        int idx = q * 256 + tid;
        int row = idx >> 4, u4 = idx & 15;
        cpu4(&w2s[row * 136 + u4 * 8], &wsb[W2B_OFF + row * 128 + u4 * 8]);
    }
    __syncthreads();

    // fwd2: M=64 N=128 K=128
    {
        const unsigned short* Ab = z1s + (w * 16 + r16) * 136 + kb * 8;
        bf16x8 a[4];
        #pragma unroll
        for (int ks = 0; ks < 4; ++ks) a[ks] = ldfrag(Ab + ks * 32);
        f32x4 acc[8] = {};
        #pragma unroll
        for (int nt = 0; nt < 8; ++nt) {
            const unsigned short* Bb = w2s + (nt * 16 + r16) * 136 + kb * 8;
            #pragma unroll
            for (int ks = 0; ks < 4; ++ks)
                acc[nt] = __builtin_amdgcn_mfma_f32_16x16x32_bf16(a[ks], ldfrag(Bb + ks * 32), acc[nt], 0, 0, 0);
        }
        int rbase = w * 16 + kb * 4;
        #pragma unroll
        for (int nt = 0; nt < 8; ++nt) {
            int col = nt * 16 + r16;
            float bb = b2[col];
            #pragma unroll
            for (int rr = 0; rr < 4; ++rr) {
                float sp, sg;
                sp_sig(acc[nt][rr] + bb, sp, sg);
                Z2g[(e0 + rbase + rr) * 128 + col] = f2bf(sp);
                S2g[(e0 + rbase + rr) * 128 + col] = f2bf(sg);
            }
        }
    }
}

// ============ K2: fwd3 (V = tanh(Z2 @ W3^T + b3)) ============
#define K2_LDS 52224
__global__ __launch_bounds__(256, 2)
void k2_fwd3(const float* __restrict__ b3,
             unsigned short* __restrict__ wsb) {
    __shared__ __align__(16) char sm[K2_LDS];
    unsigned short* z2s = (unsigned short*)(sm);            // [64][136]
    unsigned short* wc  = (unsigned short*)(sm + 17408);    // [128][136]
    const unsigned short* Z2g = wsb + Z2_OFF;
    unsigned short* Vg = wsb + V_OFF;

    const int tid = threadIdx.x;
    const int e0 = blockIdx.x * 64;
    const int lane = tid & 63;
    const int w = tid >> 6;
    const int r16 = lane & 15;
    const int kb = lane >> 4;

    #pragma unroll
    for (int q = 0; q < 4; ++q) {
        int idx = q * 256 + tid;
        int row = idx >> 4, u4 = idx & 15;
        cpu4(&z2s[row * 136 + u4 * 8], &Z2g[(e0 + row) * 128 + u4 * 8]);
    }

    for (int nc = 0; nc < 4; ++nc) {
        __syncthreads();
        #pragma unroll
        for (int q = 0; q < 8; ++q) {
            int idx = q * 256 + tid;
            int row = idx >> 4, u4 = idx & 15;
            cpu4(&wc[row * 136 + u4 * 8], &wsb[W3B_OFF + (nc * 128 + row) * 128 + u4 * 8]);
        }
        __syncthreads();

        const unsigned short* Ab = z2s + (w * 16 + r16) * 136 + kb * 8;
        bf16x8 a[4];
        #pragma unroll
        for (int ks = 0; ks < 4; ++ks) a[ks] = ldfrag(Ab + ks * 32);
        f32x4 acc[8] = {};
        #pragma unroll
        for (int nt = 0; nt < 8; ++nt) {
            const unsigned short* Bb = wc + (nt * 16 + r16) * 136 + kb * 8;
            #pragma unroll
            for (int ks = 0; ks < 4; ++ks)
                acc[nt] = __builtin_amdgcn_mfma_f32_16x16x32_bf16(a[ks], ldfrag(Bb + ks * 32), acc[nt], 0, 0, 0);
        }
        int rbase = w * 16 + kb * 4;
        #pragma unroll
        for (int nt = 0; nt < 8; ++nt) {
            int c = nc * 128 + nt * 16 + r16;
            float bb = b3[c];
            #pragma unroll
            for (int rr = 0; rr < 4; ++rr) {
                float v = tanh_fast(acc[nt][rr] + bb);
                Vg[(e0 + rbase + rr) * 512 + c] = f2bf(v);
            }
        }
    }
}

// ============ K3a: T-build + jvp1 -> dZ1 (global) ============
// grid 2048 x 256; block = 8 elements -> 64 m-rows. LDS 37120 -> 4 blocks/CU.
#define K3A_LDS 37120
__global__ __launch_bounds__(256, 4)
void k3a_jvp1(const float* __restrict__ sigg,
              unsigned short* __restrict__ wsb) {
    __shared__ __align__(16) char sm[K3A_LDS];
    unsigned short* vs  = (unsigned short*)(sm);           // [8][520]
    unsigned short* w1s = (unsigned short*)(sm + 8320);    // [128][72]
    unsigned short* ts  = (unsigned short*)(sm + 26752);   // [64][72]
    float* sigsm = (float*)(sm + 35968);                   // [288]
    const unsigned short* S1g = wsb + S1_OFF;
    const unsigned short* Vg  = wsb + V_OFF;
    unsigned short* DZ1g = wsb + DZ1_OFF;

    const int tid = threadIdx.x;
    const int e0 = blockIdx.x * 8;
    const int lane = tid & 63;
    const int w = tid >> 6;
    const int r16 = lane & 15;
    const int kb = lane >> 4;

    #pragma unroll
    for (int q = 0; q < 2; ++q) {
        int idx = q * 256 + tid;               // 0..511
        int row = idx >> 6, u4 = idx & 63;
        cpu4(&vs[row * 520 + u4 * 8], &Vg[(e0 + row) * 512 + u4 * 8]);
    }
    #pragma unroll
    for (int q = 0; q < 4; ++q) {
        int idx = q * 256 + tid;
        int row = idx >> 3, u4 = idx & 7;
        cpu4(&w1s[row * 72 + u4 * 8], &wsb[W1B_OFF + row * 64 + u4 * 8]);
    }
    #pragma unroll
    for (int q = 0; q < 2; ++q) {
        int idx = q * 256 + tid;
        if (idx < 288) sigsm[idx] = sigg[e0 * 36 + idx];
    }
    __syncthreads();

    // T-build: T[m=e*8+j][k] = sum_i c[i][j]_e * V[e][i*64+k], vectorized
    {
        int m = tid >> 2, kq = tid & 3;
        int e = m >> 3, j = m & 7;
        float c8[8];
        #pragma unroll
        for (int i = 0; i < 8; ++i) {
            float v = 0.f;
            if (i < j) {
                int p = 7 * i - i * (i - 1) / 2 + (j - i - 1);
                v = sigsm[e * 36 + 8 + p];
            } else if (i > j) {
                int p = 7 * j - j * (j - 1) / 2 + (i - j - 1);
                v = -sigsm[e * 36 + 8 + p];
            }
            c8[i] = v;
        }
        float acc[16] = {};
        #pragma unroll
        for (int i = 0; i < 8; ++i) {
            uint4 qa = *reinterpret_cast<const uint4*>(&vs[e * 520 + i * 64 + kq * 16]);
            uint4 qb = *reinterpret_cast<const uint4*>(&vs[e * 520 + i * 64 + kq * 16 + 8]);
            float fa[8], fb[8];
            unpack8(qa, fa); unpack8(qb, fb);
            #pragma unroll
            for (int kk = 0; kk < 8; ++kk) {
                acc[kk]     += c8[i] * fa[kk];
                acc[kk + 8] += c8[i] * fb[kk];
            }
        }
        unsigned short o[16];
        #pragma unroll
        for (int kk = 0; kk < 16; ++kk) o[kk] = f2bf(acc[kk]);
        uint4 qo;
        qo.x = (unsigned int)o[0] | ((unsigned int)o[1] << 16);
        qo.y = (unsigned int)o[2] | ((unsigned int)o[3] << 16);
        qo.z = (unsigned int)o[4] | ((unsigned int)o[5] << 16);
        qo.w = (unsigned int)o[6] | ((unsigned int)o[7] << 16);
        *reinterpret_cast<uint4*>(&ts[m * 72 + kq * 16]) = qo;
        qo.x = (unsigned int)o[8]  | ((unsigned int)o[9]  << 16);
        qo.y = (unsigned int)o[10] | ((unsigned int)o[11] << 16);
        qo.z = (unsigned int)o[12] | ((unsigned int)o[13] << 16);
        qo.w = (unsigned int)o[14] | ((unsigned int)o[15] << 16);
        *reinterpret_cast<uint4*>(&ts[m * 72 + kq * 16 + 8]) = qo;
    }
    __syncthreads();

    // jvp1: dZ1 = (T @ W1^T) .* s1[e]   M=64 N=128 K=64
    {
        const unsigned short* Ab = ts + (w * 16 + r16) * 72 + kb * 8;
        bf16x8 a0 = ldfrag(Ab), a1 = ldfrag(Ab + 32);
        f32x4 acc[8] = {};
        #pragma unroll
        for (int nt = 0; nt < 8; ++nt) {
            const unsigned short* Bb = w1s + (nt * 16 + r16) * 72 + kb * 8;
            acc[nt] = __builtin_amdgcn_mfma_f32_16x16x32_bf16(a0, ldfrag(Bb), acc[nt], 0, 0, 0);
            acc[nt] = __builtin_amdgcn_mfma_f32_16x16x32_bf16(a1, ldfrag(Bb + 32), acc[nt], 0, 0, 0);
        }
        int rbase = w * 16 + kb * 4;
        int e_loc = rbase >> 3;
        #pragma unroll
        for (int nt = 0; nt < 8; ++nt) {
            int col = nt * 16 + r16;
            float s1v = bf2f(S1g[(e0 + e_loc) * 128 + col]);
            #pragma unroll
            for (int rr = 0; rr < 4; ++rr)
                DZ1g[(e0 * 8 + rbase + rr) * 128 + col] = f2bf(acc[nt][rr] * s1v);
        }
    }
}

// ============ K3b: jvp2 (dZ2 = (dZ1 @ W2^T) .* s2) ============
// grid 2048 x 256; block = 64 m-rows. LDS 52224 -> 3 blocks/CU.
#define K3B_LDS 52224
__global__ __launch_bounds__(256, 3)
void k3b_jvp2(unsigned short* __restrict__ wsb) {
    __shared__ __align__(16) char sm[K3B_LDS];
    unsigned short* dz1s = (unsigned short*)(sm);           // [64][136]
    unsigned short* w2s  = (unsigned short*)(sm + 17408);   // [128][136]
    const unsigned short* S2g = wsb + S2_OFF;
    const unsigned short* DZ1g = wsb + DZ1_OFF;
    unsigned short* DZ2g = wsb + DZ2_OFF;

    const int tid = threadIdx.x;
    const int m0 = blockIdx.x * 64;
    const int lane = tid & 63;
    const int w = tid >> 6;
    const int r16 = lane & 15;
    const int kb = lane >> 4;

    #pragma unroll
    for (int q = 0; q < 4; ++q) {
        int idx = q * 256 + tid;
        int row = idx >> 4, u4 = idx & 15;
        cpu4(&dz1s[row * 136 + u4 * 8], &DZ1g[(m0 + row) * 128 + u4 * 8]);
    }
    #pragma unroll
    for (int q = 0; q < 8; ++q) {
        int idx = q * 256 + tid;
        int row = idx >> 4, u4 = idx & 15;
        cpu4(&w2s[row * 136 + u4 * 8], &wsb[W2B_OFF + row * 128 + u4 * 8]);
    }
    __syncthreads();

    const unsigned short* Ab = dz1s + (w * 16 + r16) * 136 + kb * 8;
    bf16x8 a[4];
    #pragma unroll
    for (int ks = 0; ks < 4; ++ks) a[ks] = ldfrag(Ab + ks * 32);
    f32x4 acc[8] = {};
    #pragma unroll
    for (int nt = 0; nt < 8; ++nt) {
        const unsigned short* Bb = w2s + (nt * 16 + r16) * 136 + kb * 8;
        #pragma unroll
        for (int ks = 0; ks < 4; ++ks)
            acc[nt] = __builtin_amdgcn_mfma_f32_16x16x32_bf16(a[ks], ldfrag(Bb + ks * 32), acc[nt], 0, 0, 0);
    }
    int rbase = w * 16 + kb * 4;
    int e_glob = (m0 + rbase) >> 3;
    #pragma unroll
    for (int nt = 0; nt < 8; ++nt) {
        int col = nt * 16 + r16;
        float s2v = bf2f(S2g[e_glob * 128 + col]);
        #pragma unroll
        for (int rr = 0; rr < 4; ++rr)
            DZ2g[(m0 + rbase + rr) * 128 + col] = f2bf(acc[nt][rr] * s2v);
    }
}

// ============ K4: jvp3 + mask + level-1, register accumulation over j ============
// grid 256 x 256; block = 64 elements, loop j=0..7. LDS 37120 -> 4 blocks/CU.
#define K4_LDS 37120
__global__ __launch_bounds__(256, 4)
void k4_jvp3(const float* __restrict__ sigg,
             const unsigned short* __restrict__ wsb,
             float* __restrict__ out) {
    __shared__ __align__(16) char sm[K4_LDS];
    unsigned short* adz = (unsigned short*)(sm);            // [64][136]
    unsigned short* w3j = (unsigned short*)(sm + 17408);    // [64][136]
    float*          sg1 = (float*)(sm + 34816);             // [64][9]
    const unsigned short* Vg = wsb + V_OFF;
    const unsigned short* DZ2g = wsb + DZ2_OFF;

    const int tid = threadIdx.x;
    const int e0 = blockIdx.x * 64;
    const int lane = tid & 63;
    const int w = tid >> 6;
    const int r16 = lane & 15;
    const int kb = lane >> 4;
    const int rbase = w * 16 + kb * 4;

    // stage level-1 signature coefficients
    #pragma unroll
    for (int q = 0; q < 2; ++q) {
        int idx = q * 256 + tid;               // 0..511
        int e = idx >> 3, j7 = idx & 7;
        sg1[e * 9 + j7] = sigg[(e0 + e) * 36 + j7];
    }

    float oacc[4][4] = {};

    for (int j = 0; j < 8; ++j) {
        __syncthreads();   // LDS buffers reusable (also covers sg1 on first iter)
        #pragma unroll
        for (int q = 0; q < 4; ++q) {
            int idx = q * 256 + tid;
            int row = idx >> 4, u4 = idx & 15;
            cpu4(&adz[row * 136 + u4 * 8], &DZ2g[((e0 + row) * 8 + j) * 128 + u4 * 8]);
            cpu4(&w3j[row * 136 + u4 * 8], &wsb[W3B_OFF + (j * 64 + row) * 128 + u4 * 8]);
        }
        __syncthreads();

        const unsigned short* Ab = adz + (w * 16 + r16) * 136 + kb * 8;
        bf16x8 a[4];
        #pragma unroll
        for (int ks = 0; ks < 4; ++ks) a[ks] = ldfrag(Ab + ks * 32);
        f32x4 acc[4] = {};
        #pragma unroll
        for (int nt = 0; nt < 4; ++nt) {
            const unsigned short* Bb = w3j + (nt * 16 + r16) * 136 + kb * 8;
            #pragma unroll
            for (int ks = 0; ks < 4; ++ks)
                acc[nt] = __builtin_amdgcn_mfma_f32_16x16x32_bf16(a[ks], ldfrag(Bb + ks * 32), acc[nt], 0, 0, 0);
        }
        #pragma unroll
        for (int nt = 0; nt < 4; ++nt) {
            int np = nt * 16 + r16;
            #pragma unroll
            for (int rr = 0; rr < 4; ++rr) {
                int e = e0 + rbase + rr;
                float v = bf2f(Vg[e * 512 + j * 64 + np]);
                float sv = sg1[(rbase + rr) * 9 + j];
                oacc[nt][rr] += sv * v + (1.f - v * v) * acc[nt][rr];
            }
        }
    }

    #pragma unroll
    for (int nt = 0; nt < 4; ++nt) {
        int np = nt * 16 + r16;
        #pragma unroll
        for (int rr = 0; rr < 4; ++rr)
            out[(e0 + rbase + rr) * 64 + np] = oacc[nt][rr];
    }
}

extern "C" void kernel_launch(void* const* d_in, const int* in_sizes, int n_in,
                              void* d_out, int out_size, void* d_ws, size_t ws_size,
                              hipStream_t stream) {
    const float* hg  = (const float*)d_in[0];
    const float* sg  = (const float*)d_in[1];
    const float* W1  = (const float*)d_in[2];
    const float* b1  = (const float*)d_in[3];
    const float* W2  = (const float*)d_in[4];
    const float* b2  = (const float*)d_in[5];
    const float* W3  = (const float*)d_in[6];
    const float* b3  = (const float*)d_in[7];
    float* outp = (float*)d_out;
    unsigned short* wsb = (unsigned short*)d_ws;

    hipLaunchKernelGGL(prep_weights, dim3((WS_WEIGHTS + 255) / 256), dim3(256), 0, stream,
                       W1, W2, W3, wsb);
    hipLaunchKernelGGL(k1_fwd12, dim3(NEL / 64), dim3(256), 0, stream, hg, b1, b2, wsb);
    hipLaunchKernelGGL(k2_fwd3,  dim3(NEL / 64), dim3(256), 0, stream, b3, wsb);
    hipLaunchKernelGGL(k3a_jvp1, dim3(NEL / 8),  dim3(256), 0, stream, sg, wsb);
    hipLaunchKernelGGL(k3b_jvp2, dim3(NEL * 8 / 64), dim3(256), 0, stream, wsb);
    hipLaunchKernelGGL(k4_jvp3,  dim3(NEL / 64), dim3(256), 0, stream, sg, wsb, outp);
}

// Round 9
// 78.301 us; speedup vs baseline: 1.7253x; 1.0572x over previous
//
#include <hip/hip_runtime.h>
#include <hip/hip_bf16.h>

#define NEL 16384

// ---- workspace layout (offsets in SHORTS from d_ws base) ----
#define W1B_OFF 0                         // bf16 W1 [128][64]
#define W2B_OFF 8192                      // bf16 W2 [128][128]
#define W3B_OFF 24576                     // bf16 W3 [512][128]
#define WS_WEIGHTS 90112
#define S1_OFF  90112                     // bf16 [NEL][128]
#define S2_OFF  (S1_OFF + NEL*128)
#define Z2_OFF  (S2_OFF + NEL*128)
#define V_OFF   (Z2_OFF + NEL*128)        // bf16 [NEL][512]
#define DZ1_OFF (V_OFF + NEL*512)         // bf16 [NEL*8][128]  (row m = e*8+j)
#define DZ2_OFF (DZ1_OFF + NEL*8*128)     // bf16 [NEL*8][128]

typedef __attribute__((ext_vector_type(8))) short bf16x8;
typedef __attribute__((ext_vector_type(4))) float f32x4;

__device__ __forceinline__ float bf2f(unsigned int u16) {
    unsigned int x = u16 << 16;
    float f; __builtin_memcpy(&f, &x, 4); return f;
}
__device__ __forceinline__ unsigned short f2bf(float f) {
    unsigned int x; __builtin_memcpy(&x, &f, 4);
    x = (x + 0x7FFFu + ((x >> 16) & 1u)) >> 16;
    return (unsigned short)x;
}
__device__ __forceinline__ void unpack8(uint4 q, float* f) {
    f[0] = bf2f(q.x & 0xFFFFu); f[1] = bf2f(q.x >> 16);
    f[2] = bf2f(q.y & 0xFFFFu); f[3] = bf2f(q.y >> 16);
    f[4] = bf2f(q.z & 0xFFFFu); f[5] = bf2f(q.z >> 16);
    f[6] = bf2f(q.w & 0xFFFFu); f[7] = bf2f(q.w >> 16);
}
__device__ __forceinline__ void sp_sig(float x, float& sp, float& sig) {
    float t = __expf(-fabsf(x));
    float r = __builtin_amdgcn_rcpf(1.f + t);
    sig = (x >= 0.f) ? r : 1.f - r;
    sp  = fmaxf(x, 0.f) + __logf(1.f + t);
}
__device__ __forceinline__ float tanh_fast(float x) {
    float t = __expf(-2.f * fabsf(x));
    float y = (1.f - t) * __builtin_amdgcn_rcpf(1.f + t);
    unsigned int xb, yb;
    __builtin_memcpy(&xb, &x, 4);
    __builtin_memcpy(&yb, &y, 4);
    yb |= (xb & 0x80000000u);
    float rr; __builtin_memcpy(&rr, &yb, 4);
    return rr;
}
__device__ __forceinline__ bf16x8 ldfrag(const unsigned short* p) {
    return *reinterpret_cast<const bf16x8*>(p);
}
__device__ __forceinline__ void cpu4(unsigned short* dst, const unsigned short* src) {
    *reinterpret_cast<uint4*>(dst) = *reinterpret_cast<const uint4*>(src);
}

// ---- prep: bf16 copies of W1, W2, W3 in [out][k] layout ----
__global__ void prep_weights(const float* __restrict__ W1,
                             const float* __restrict__ W2,
                             const float* __restrict__ W3,
                             unsigned short* __restrict__ wb) {
    int i = blockIdx.x * blockDim.x + threadIdx.x;
    if (i >= WS_WEIGHTS) return;
    float v;
    if (i < W2B_OFF) v = W1[i];
    else if (i < W3B_OFF) v = W2[i - W2B_OFF];
    else v = W3[i - W3B_OFF];
    wb[i] = f2bf(v);
}

// ============ K1: fwd1 + fwd2, 16 elems/block, grid 1024, 4 blocks/CU ============
// LDS: phase1 W1s[128][72]@0 + hs[16][72]@18432; phase2 W2s[128][136]@0 (overlay);
//      z1s[16][136]@34816. Total 39168.
#define K1_LDS 39168
__global__ __launch_bounds__(256, 4)
void k1_fwd12(const float* __restrict__ hg,
              const float* __restrict__ b1,
              const float* __restrict__ b2,
              unsigned short* __restrict__ wsb) {
    __shared__ __align__(16) char sm[K1_LDS];
    unsigned short* w1s = (unsigned short*)(sm);            // [128][72]
    unsigned short* hs  = (unsigned short*)(sm + 18432);    // [16][72]
    unsigned short* w2s = (unsigned short*)(sm);            // [128][136] phase2
    unsigned short* z1s = (unsigned short*)(sm + 34816);    // [16][136]
    unsigned short* S1g = wsb + S1_OFF;
    unsigned short* S2g = wsb + S2_OFF;
    unsigned short* Z2g = wsb + Z2_OFF;

    const int tid = threadIdx.x;
    const int e0 = blockIdx.x * 16;
    const int lane = tid & 63;
    const int w = tid >> 6;            // wave 0..3
    const int r16 = lane & 15;
    const int kb = lane >> 4;
    const int crow = kb * 4;

    // stage W1s (1024 uint4, 4/thread) + hs (256 float4 -> bf16x4)
    #pragma unroll
    for (int q = 0; q < 4; ++q) {
        int idx = q * 256 + tid;
        int row = idx >> 3, u4 = idx & 7;
        cpu4(&w1s[row * 72 + u4 * 8], &wsb[W1B_OFF + row * 64 + u4 * 8]);
    }
    {
        int row = tid >> 4, f4 = tid & 15;
        float4 hv = *reinterpret_cast<const float4*>(&hg[(e0 + row) * 64 + f4 * 4]);
        ushort2 lo = { f2bf(hv.x), f2bf(hv.y) };
        ushort2 hi = { f2bf(hv.z), f2bf(hv.w) };
        *reinterpret_cast<ushort2*>(&hs[row * 72 + f4 * 4]) = lo;
        *reinterpret_cast<ushort2*>(&hs[row * 72 + f4 * 4 + 2]) = hi;
    }
    __syncthreads();

    // fwd1: M=16 N=128 K=64; wave w -> n-tiles w*2, w*2+1
    {
        const unsigned short* Ab = hs + r16 * 72 + kb * 8;
        bf16x8 a0 = ldfrag(Ab), a1 = ldfrag(Ab + 32);
        f32x4 acc[2] = {};
        #pragma unroll
        for (int t = 0; t < 2; ++t) {
            int col16 = (w * 2 + t) * 16 + r16;
            const unsigned short* Bb = w1s + col16 * 72 + kb * 8;
            acc[t] = __builtin_amdgcn_mfma_f32_16x16x32_bf16(a0, ldfrag(Bb), acc[t], 0, 0, 0);
            acc[t] = __builtin_amdgcn_mfma_f32_16x16x32_bf16(a1, ldfrag(Bb + 32), acc[t], 0, 0, 0);
        }
        #pragma unroll
        for (int t = 0; t < 2; ++t) {
            int col = (w * 2 + t) * 16 + r16;
            float bb = b1[col];
            #pragma unroll
            for (int rr = 0; rr < 4; ++rr) {
                int e = crow + rr;
                float sp, sg;
                sp_sig(acc[t][rr] + bb, sp, sg);
                z1s[e * 136 + col] = f2bf(sp);
                S1g[(e0 + e) * 128 + col] = f2bf(sg);
            }
        }
    }
    __syncthreads();

    // stage W2s (2048 uint4, 8/thread)
    #pragma unroll
    for (int q = 0; q < 8; ++q) {
        int idx = q * 256 + tid;
        int row = idx >> 4, u4 = idx & 15;
        cpu4(&w2s[row * 136 + u4 * 8], &wsb[W2B_OFF + row * 128 + u4 * 8]);
    }
    __syncthreads();

    // fwd2: M=16 N=128 K=128
    {
        const unsigned short* Ab = z1s + r16 * 136 + kb * 8;
        bf16x8 a[4];
        #pragma unroll
        for (int ks = 0; ks < 4; ++ks) a[ks] = ldfrag(Ab + ks * 32);
        f32x4 acc[2] = {};
        #pragma unroll
        for (int t = 0; t < 2; ++t) {
            int col16 = (w * 2 + t) * 16 + r16;
            const unsigned short* Bb = w2s + col16 * 136 + kb * 8;
            #pragma unroll
            for (int ks = 0; ks < 4; ++ks)
                acc[t] = __builtin_amdgcn_mfma_f32_16x16x32_bf16(a[ks], ldfrag(Bb + ks * 32), acc[t], 0, 0, 0);
        }
        #pragma unroll
        for (int t = 0; t < 2; ++t) {
            int col = (w * 2 + t) * 16 + r16;
            float bb = b2[col];
            #pragma unroll
            for (int rr = 0; rr < 4; ++rr) {
                int e = crow + rr;
                float sp, sg;
                sp_sig(acc[t][rr] + bb, sp, sg);
                Z2g[(e0 + e) * 128 + col] = f2bf(sp);
                S2g[(e0 + e) * 128 + col] = f2bf(sg);
            }
        }
    }
}

// ============ K2: fwd3, 16 elems/block, grid 1024, 4 blocks/CU ============
// LDS: z2s[16][136]@0 (4352) + wc[128][136]@4352 (34816) = 39168
#define K2_LDS 39168
__global__ __launch_bounds__(256, 4)
void k2_fwd3(const float* __restrict__ b3,
             unsigned short* __restrict__ wsb) {
    __shared__ __align__(16) char sm[K2_LDS];
    unsigned short* z2s = (unsigned short*)(sm);            // [16][136]
    unsigned short* wc  = (unsigned short*)(sm + 4352);     // [128][136]
    const unsigned short* Z2g = wsb + Z2_OFF;
    unsigned short* Vg = wsb + V_OFF;

    const int tid = threadIdx.x;
    const int e0 = blockIdx.x * 16;
    const int lane = tid & 63;
    const int w = tid >> 6;
    const int r16 = lane & 15;
    const int kb = lane >> 4;
    const int crow = kb * 4;

    // stage z2s (256 uint4, 1/thread)
    {
        int row = tid >> 4, u4 = tid & 15;
        cpu4(&z2s[row * 136 + u4 * 8], &Z2g[(e0 + row) * 128 + u4 * 8]);
    }

    for (int nc = 0; nc < 4; ++nc) {
        __syncthreads();
        #pragma unroll
        for (int q = 0; q < 8; ++q) {
            int idx = q * 256 + tid;
            int row = idx >> 4, u4 = idx & 15;
            cpu4(&wc[row * 136 + u4 * 8], &wsb[W3B_OFF + (nc * 128 + row) * 128 + u4 * 8]);
        }
        __syncthreads();

        const unsigned short* Ab = z2s + r16 * 136 + kb * 8;
        bf16x8 a[4];
        #pragma unroll
        for (int ks = 0; ks < 4; ++ks) a[ks] = ldfrag(Ab + ks * 32);
        f32x4 acc[2] = {};
        #pragma unroll
        for (int t = 0; t < 2; ++t) {
            int col16 = (w * 2 + t) * 16 + r16;
            const unsigned short* Bb = wc + col16 * 136 + kb * 8;
            #pragma unroll
            for (int ks = 0; ks < 4; ++ks)
                acc[t] = __builtin_amdgcn_mfma_f32_16x16x32_bf16(a[ks], ldfrag(Bb + ks * 32), acc[t], 0, 0, 0);
        }
        #pragma unroll
        for (int t = 0; t < 2; ++t) {
            int c = nc * 128 + (w * 2 + t) * 16 + r16;
            float bb = b3[c];
            #pragma unroll
            for (int rr = 0; rr < 4; ++rr) {
                int e = crow + rr;
                float v = tanh_fast(acc[t][rr] + bb);
                Vg[(e0 + e) * 512 + c] = f2bf(v);
            }
        }
    }
}

// ============ K3a: T-build + jvp1 -> dZ1 (global), 8 elems/block ============
// grid 2048; LDS 37120 -> 4 blocks/CU.
#define K3A_LDS 37120
__global__ __launch_bounds__(256, 4)
void k3a_jvp1(const float* __restrict__ sigg,
              unsigned short* __restrict__ wsb) {
    __shared__ __align__(16) char sm[K3A_LDS];
    unsigned short* vs  = (unsigned short*)(sm);           // [8][520]
    unsigned short* w1s = (unsigned short*)(sm + 8320);    // [128][72]
    unsigned short* ts  = (unsigned short*)(sm + 26752);   // [64][72]
    float* sigsm = (float*)(sm + 35968);                   // [288]
    const unsigned short* S1g = wsb + S1_OFF;
    const unsigned short* Vg  = wsb + V_OFF;
    unsigned short* DZ1g = wsb + DZ1_OFF;

    const int tid = threadIdx.x;
    const int e0 = blockIdx.x * 8;
    const int lane = tid & 63;
    const int w = tid >> 6;
    const int r16 = lane & 15;
    const int kb = lane >> 4;

    #pragma unroll
    for (int q = 0; q < 2; ++q) {
        int idx = q * 256 + tid;               // 0..511
        int row = idx >> 6, u4 = idx & 63;
        cpu4(&vs[row * 520 + u4 * 8], &Vg[(e0 + row) * 512 + u4 * 8]);
    }
    #pragma unroll
    for (int q = 0; q < 4; ++q) {
        int idx = q * 256 + tid;
        int row = idx >> 3, u4 = idx & 7;
        cpu4(&w1s[row * 72 + u4 * 8], &wsb[W1B_OFF + row * 64 + u4 * 8]);
    }
    #pragma unroll
    for (int q = 0; q < 2; ++q) {
        int idx = q * 256 + tid;
        if (idx < 288) sigsm[idx] = sigg[e0 * 36 + idx];
    }
    __syncthreads();

    // T-build: T[m=e*8+j][k] = sum_i c[i][j]_e * V[e][i*64+k]
    {
        int m = tid >> 2, kq = tid & 3;
        int e = m >> 3, j = m & 7;
        float c8[8];
        #pragma unroll
        for (int i = 0; i < 8; ++i) {
            float v = 0.f;
            if (i < j) {
                int p = 7 * i - i * (i - 1) / 2 + (j - i - 1);
                v = sigsm[e * 36 + 8 + p];
            } else if (i > j) {
                int p = 7 * j - j * (j - 1) / 2 + (i - j - 1);
                v = -sigsm[e * 36 + 8 + p];
            }
            c8[i] = v;
        }
        float acc[16] = {};
        #pragma unroll
        for (int i = 0; i < 8; ++i) {
            uint4 qa = *reinterpret_cast<const uint4*>(&vs[e * 520 + i * 64 + kq * 16]);
            uint4 qb = *reinterpret_cast<const uint4*>(&vs[e * 520 + i * 64 + kq * 16 + 8]);
            float fa[8], fb[8];
            unpack8(qa, fa); unpack8(qb, fb);
            #pragma unroll
            for (int kk = 0; kk < 8; ++kk) {
                acc[kk]     += c8[i] * fa[kk];
                acc[kk + 8] += c8[i] * fb[kk];
            }
        }
        unsigned short o[16];
        #pragma unroll
        for (int kk = 0; kk < 16; ++kk) o[kk] = f2bf(acc[kk]);
        uint4 qo;
        qo.x = (unsigned int)o[0] | ((unsigned int)o[1] << 16);
        qo.y = (unsigned int)o[2] | ((unsigned int)o[3] << 16);
        qo.z = (unsigned int)o[4] | ((unsigned int)o[5] << 16);
        qo.w = (unsigned int)o[6] | ((unsigned int)o[7] << 16);
        *reinterpret_cast<uint4*>(&ts[m * 72 + kq * 16]) = qo;
        qo.x = (unsigned int)o[8]  | ((unsigned int)o[9]  << 16);
        qo.y = (unsigned int)o[10] | ((unsigned int)o[11] << 16);
        qo.z = (unsigned int)o[12] | ((unsigned int)o[13] << 16);
        qo.w = (unsigned int)o[14] | ((unsigned int)o[15] << 16);
        *reinterpret_cast<uint4*>(&ts[m * 72 + kq * 16 + 8]) = qo;
    }
    __syncthreads();

    // jvp1: dZ1 = (T @ W1^T) .* s1[e]   M=64 N=128 K=64
    {
        const unsigned short* Ab = ts + (w * 16 + r16) * 72 + kb * 8;
        bf16x8 a0 = ldfrag(Ab), a1 = ldfrag(Ab + 32);
        f32x4 acc[8] = {};
        #pragma unroll
        for (int nt = 0; nt < 8; ++nt) {
            const unsigned short* Bb = w1s + (nt * 16 + r16) * 72 + kb * 8;
            acc[nt] = __builtin_amdgcn_mfma_f32_16x16x32_bf16(a0, ldfrag(Bb), acc[nt], 0, 0, 0);
            acc[nt] = __builtin_amdgcn_mfma_f32_16x16x32_bf16(a1, ldfrag(Bb + 32), acc[nt], 0, 0, 0);
        }
        int rbase = w * 16 + kb * 4;
        int e_loc = rbase >> 3;
        #pragma unroll
        for (int nt = 0; nt < 8; ++nt) {
            int col = nt * 16 + r16;
            float s1v = bf2f(S1g[(e0 + e_loc) * 128 + col]);
            #pragma unroll
            for (int rr = 0; rr < 4; ++rr)
                DZ1g[(e0 * 8 + rbase + rr) * 128 + col] = f2bf(acc[nt][rr] * s1v);
        }
    }
}

// ============ K3b: jvp2, 32 m-rows/block, grid 4096, 3 blocks/CU ============
// LDS: dz1s[32][136]@0 (8704) + w2s[128][136]@8704 (34816) = 43520
#define K3B_LDS 43520
__global__ __launch_bounds__(256, 3)
void k3b_jvp2(unsigned short* __restrict__ wsb) {
    __shared__ __align__(16) char sm[K3B_LDS];
    unsigned short* dz1s = (unsigned short*)(sm);           // [32][136]
    unsigned short* w2s  = (unsigned short*)(sm + 8704);    // [128][136]
    const unsigned short* S2g = wsb + S2_OFF;
    const unsigned short* DZ1g = wsb + DZ1_OFF;
    unsigned short* DZ2g = wsb + DZ2_OFF;

    const int tid = threadIdx.x;
    const int m0 = blockIdx.x * 32;
    const int lane = tid & 63;
    const int w = tid >> 6;
    const int r16 = lane & 15;
    const int kb = lane >> 4;
    const int mt = w & 1, nh = w >> 1;

    #pragma unroll
    for (int q = 0; q < 2; ++q) {
        int idx = q * 256 + tid;               // 0..511
        int row = idx >> 4, u4 = idx & 15;
        cpu4(&dz1s[row * 136 + u4 * 8], &DZ1g[(m0 + row) * 128 + u4 * 8]);
    }
    #pragma unroll
    for (int q = 0; q < 8; ++q) {
        int idx = q * 256 + tid;
        int row = idx >> 4, u4 = idx & 15;
        cpu4(&w2s[row * 136 + u4 * 8], &wsb[W2B_OFF + row * 128 + u4 * 8]);
    }
    __syncthreads();

    const unsigned short* Ab = dz1s + (mt * 16 + r16) * 136 + kb * 8;
    bf16x8 a[4];
    #pragma unroll
    for (int ks = 0; ks < 4; ++ks) a[ks] = ldfrag(Ab + ks * 32);
    f32x4 acc[4] = {};
    #pragma unroll
    for (int nt = 0; nt < 4; ++nt) {
        const unsigned short* Bb = w2s + ((nh * 4 + nt) * 16 + r16) * 136 + kb * 8;
        #pragma unroll
        for (int ks = 0; ks < 4; ++ks)
            acc[nt] = __builtin_amdgcn_mfma_f32_16x16x32_bf16(a[ks], ldfrag(Bb + ks * 32), acc[nt], 0, 0, 0);
    }
    int rbase = mt * 16 + kb * 4;
    int e_glob = (m0 + rbase) >> 3;            // constant across rr (rbase % 4 == 0)
    #pragma unroll
    for (int nt = 0; nt < 4; ++nt) {
        int col = (nh * 4 + nt) * 16 + r16;
        float s2v = bf2f(S2g[e_glob * 128 + col]);
        #pragma unroll
        for (int rr = 0; rr < 4; ++rr)
            DZ2g[(m0 + rbase + rr) * 128 + col] = f2bf(acc[nt][rr] * s2v);
    }
}

// ============ K4: jvp3 + mask + level-1, 16 elems/block, grid 1024 ============
// LDS: adz[16][136]@0 (4352) + w3j[64][136]@4352 (17408) + sg1[16][9]f32@21760 (576) = 22336
#define K4_LDS 22336
__global__ __launch_bounds__(256, 4)
void k4_jvp3(const float* __restrict__ sigg,
             const unsigned short* __restrict__ wsb,
             float* __restrict__ out) {
    __shared__ __align__(16) char sm[K4_LDS];
    unsigned short* adz = (unsigned short*)(sm);            // [16][136]
    unsigned short* w3j = (unsigned short*)(sm + 4352);     // [64][136]
    float*          sg1 = (float*)(sm + 21760);             // [16][9]
    const unsigned short* Vg = wsb + V_OFF;
    const unsigned short* DZ2g = wsb + DZ2_OFF;

    const int tid = threadIdx.x;
    const int e0 = blockIdx.x * 16;
    const int lane = tid & 63;
    const int w = tid >> 6;            // wave w -> n-tile w (cols w*16..+15)
    const int r16 = lane & 15;
    const int kb = lane >> 4;
    const int crow = kb * 4;
    const int np = w * 16 + r16;

    if (tid < 128) {
        int e = tid >> 3, j7 = tid & 7;
        sg1[e * 9 + j7] = sigg[(e0 + e) * 36 + j7];
    }

    float oacc[4] = {};

    for (int j = 0; j < 8; ++j) {
        __syncthreads();
        {
            int row = tid >> 4, u4 = tid & 15;   // adz: 256 uint4
            cpu4(&adz[row * 136 + u4 * 8], &DZ2g[((e0 + row) * 8 + j) * 128 + u4 * 8]);
        }
        #pragma unroll
        for (int q = 0; q < 4; ++q) {
            int idx = q * 256 + tid;             // w3j: 1024 uint4
            int row = idx >> 4, u4 = idx & 15;
            cpu4(&w3j[row * 136 + u4 * 8], &wsb[W3B_OFF + (j * 64 + row) * 128 + u4 * 8]);
        }
        __syncthreads();

        const unsigned short* Ab = adz + r16 * 136 + kb * 8;
        bf16x8 a[4];
        #pragma unroll
        for (int ks = 0; ks < 4; ++ks) a[ks] = ldfrag(Ab + ks * 32);
        f32x4 acc = {};
        const unsigned short* Bb = w3j + np * 136 + kb * 8;
        #pragma unroll
        for (int ks = 0; ks < 4; ++ks)
            acc = __builtin_amdgcn_mfma_f32_16x16x32_bf16(a[ks], ldfrag(Bb + ks * 32), acc, 0, 0, 0);

        #pragma unroll
        for (int rr = 0; rr < 4; ++rr) {
            int e = crow + rr;
            float v = bf2f(Vg[(e0 + e) * 512 + j * 64 + np]);
            float sv = sg1[e * 9 + j];
            oacc[rr] += sv * v + (1.f - v * v) * acc[rr];
        }
    }

    #pragma unroll
    for (int rr = 0; rr < 4; ++rr)
        out[(e0 + crow + rr) * 64 + np] = oacc[rr];
}

extern "C" void kernel_launch(void* const* d_in, const int* in_sizes, int n_in,
                              void* d_out, int out_size, void* d_ws, size_t ws_size,
                              hipStream_t stream) {
    const float* hg  = (const float*)d_in[0];
    const float* sg  = (const float*)d_in[1];
    const float* W1  = (const float*)d_in[2];
    const float* b1  = (const float*)d_in[3];
    const float* W2  = (const float*)d_in[4];
    const float* b2  = (const float*)d_in[5];
    const float* W3  = (const float*)d_in[6];
    const float* b3  = (const float*)d_in[7];
    float* outp = (float*)d_out;
    unsigned short* wsb = (unsigned short*)d_ws;

    hipLaunchKernelGGL(prep_weights, dim3((WS_WEIGHTS + 255) / 256), dim3(256), 0, stream,
                       W1, W2, W3, wsb);
    hipLaunchKernelGGL(k1_fwd12, dim3(NEL / 16), dim3(256), 0, stream, hg, b1, b2, wsb);
    hipLaunchKernelGGL(k2_fwd3,  dim3(NEL / 16), dim3(256), 0, stream, b3, wsb);
    hipLaunchKernelGGL(k3a_jvp1, dim3(NEL / 8),  dim3(256), 0, stream, sg, wsb);
    hipLaunchKernelGGL(k3b_jvp2, dim3(NEL * 8 / 32), dim3(256), 0, stream, wsb);
    hipLaunchKernelGGL(k4_jvp3,  dim3(NEL / 16), dim3(256), 0, stream, sg, wsb, outp);
}

// Round 11
// 76.286 us; speedup vs baseline: 1.7709x; 1.0264x over previous
//
#include <hip/hip_runtime.h>
#include <hip/hip_bf16.h>

#define NEL 16384

// ---- workspace layout (offsets in SHORTS from d_ws base) ----
#define W1B_OFF 0                         // bf16 W1 [128][64]
#define W2B_OFF 8192                      // bf16 W2 [128][128]
#define W3B_OFF 24576                     // bf16 W3 [512][128]
#define WS_WEIGHTS 90112
#define S1_OFF  90112                     // bf16 [NEL][128]
#define S2_OFF  (S1_OFF + NEL*128)
#define V_OFF   (S2_OFF + NEL*128)        // bf16 [NEL][512]
#define DZ2_OFF (V_OFF + NEL*512)         // bf16 [NEL*8][128]  (row m = e*8+j)

typedef __attribute__((ext_vector_type(8))) short bf16x8;
typedef __attribute__((ext_vector_type(4))) float f32x4;

__device__ __forceinline__ float bf2f(unsigned int u16) {
    unsigned int x = u16 << 16;
    float f; __builtin_memcpy(&f, &x, 4); return f;
}
__device__ __forceinline__ unsigned short f2bf(float f) {
    unsigned int x; __builtin_memcpy(&x, &f, 4);
    x = (x + 0x7FFFu + ((x >> 16) & 1u)) >> 16;
    return (unsigned short)x;
}
__device__ __forceinline__ void unpack8(uint4 q, float* f) {
    f[0] = bf2f(q.x & 0xFFFFu); f[1] = bf2f(q.x >> 16);
    f[2] = bf2f(q.y & 0xFFFFu); f[3] = bf2f(q.y >> 16);
    f[4] = bf2f(q.z & 0xFFFFu); f[5] = bf2f(q.z >> 16);
    f[6] = bf2f(q.w & 0xFFFFu); f[7] = bf2f(q.w >> 16);
}
__device__ __forceinline__ void sp_sig(float x, float& sp, float& sig) {
    float t = __expf(-fabsf(x));
    float r = __builtin_amdgcn_rcpf(1.f + t);
    sig = (x >= 0.f) ? r : 1.f - r;
    sp  = fmaxf(x, 0.f) + __logf(1.f + t);
}
__device__ __forceinline__ float tanh_fast(float x) {
    float t = __expf(-2.f * fabsf(x));
    float y = (1.f - t) * __builtin_amdgcn_rcpf(1.f + t);
    unsigned int xb, yb;
    __builtin_memcpy(&xb, &x, 4);
    __builtin_memcpy(&yb, &y, 4);
    yb |= (xb & 0x80000000u);
    float rr; __builtin_memcpy(&rr, &yb, 4);
    return rr;
}
__device__ __forceinline__ bf16x8 ldfrag(const unsigned short* p) {
    return *reinterpret_cast<const bf16x8*>(p);
}
__device__ __forceinline__ void cpu4(unsigned short* dst, const unsigned short* src) {
    *reinterpret_cast<uint4*>(dst) = *reinterpret_cast<const uint4*>(src);
}

// ---- prep: bf16 copies of W1, W2, W3 in [out][k] layout ----
__global__ void prep_weights(const float* __restrict__ W1,
                             const float* __restrict__ W2,
                             const float* __restrict__ W3,
                             unsigned short* __restrict__ wb) {
    int i = blockIdx.x * blockDim.x + threadIdx.x;
    if (i >= WS_WEIGHTS) return;
    float v;
    if (i < W2B_OFF) v = W1[i];
    else if (i < W3B_OFF) v = W2[i - W2B_OFF];
    else v = W3[i - W3B_OFF];
    wb[i] = f2bf(v);
}

// ============ K12: fwd1 + fwd2 + fwd3 (Z1, Z2 stay in LDS) ============
// 16 elems/block, grid 1024, 4 blocks/CU.
// LDS: w1s[128][72]@0 + hs[16][72]@18432 | w2s[128][136]@0 | wc[128][136]@0
//      z1s[16][136]@34816 -> z2s overlays z1s (RACE-protected: A-frags are
//      register-held behind a barrier before the overlay write). Total 39168.
#define K12_LDS 39168
__global__ __launch_bounds__(256, 4)
void k12_fwd(const float* __restrict__ hg,
             const float* __restrict__ b1,
             const float* __restrict__ b2,
             const float* __restrict__ b3,
             unsigned short* __restrict__ wsb) {
    __shared__ __align__(16) char sm[K12_LDS];
    unsigned short* w1s = (unsigned short*)(sm);            // [128][72]
    unsigned short* hs  = (unsigned short*)(sm + 18432);    // [16][72]
    unsigned short* w2s = (unsigned short*)(sm);            // [128][136] phase2
    unsigned short* wc  = (unsigned short*)(sm);            // [128][136] phase3 (per chunk)
    unsigned short* z1s = (unsigned short*)(sm + 34816);    // [16][136]
    unsigned short* z2s = (unsigned short*)(sm + 34816);    // [16][136] overlays z1s
    unsigned short* S1g = wsb + S1_OFF;
    unsigned short* S2g = wsb + S2_OFF;
    unsigned short* Vg  = wsb + V_OFF;

    const int tid = threadIdx.x;
    const int e0 = blockIdx.x * 16;
    const int lane = tid & 63;
    const int w = tid >> 6;            // wave 0..3
    const int r16 = lane & 15;
    const int kb = lane >> 4;
    const int crow = kb * 4;

    // stage W1s (1024 uint4) + hs (256 float4 -> bf16x4)
    #pragma unroll
    for (int q = 0; q < 4; ++q) {
        int idx = q * 256 + tid;
        int row = idx >> 3, u4 = idx & 7;
        cpu4(&w1s[row * 72 + u4 * 8], &wsb[W1B_OFF + row * 64 + u4 * 8]);
    }
    {
        int row = tid >> 4, f4 = tid & 15;
        float4 hv = *reinterpret_cast<const float4*>(&hg[(e0 + row) * 64 + f4 * 4]);
        ushort2 lo = { f2bf(hv.x), f2bf(hv.y) };
        ushort2 hi = { f2bf(hv.z), f2bf(hv.w) };
        *reinterpret_cast<ushort2*>(&hs[row * 72 + f4 * 4]) = lo;
        *reinterpret_cast<ushort2*>(&hs[row * 72 + f4 * 4 + 2]) = hi;
    }
    __syncthreads();

    // fwd1: M=16 N=128 K=64
    {
        const unsigned short* Ab = hs + r16 * 72 + kb * 8;
        bf16x8 a0 = ldfrag(Ab), a1 = ldfrag(Ab + 32);
        f32x4 acc[2] = {};
        #pragma unroll
        for (int t = 0; t < 2; ++t) {
            int col16 = (w * 2 + t) * 16 + r16;
            const unsigned short* Bb = w1s + col16 * 72 + kb * 8;
            acc[t] = __builtin_amdgcn_mfma_f32_16x16x32_bf16(a0, ldfrag(Bb), acc[t], 0, 0, 0);
            acc[t] = __builtin_amdgcn_mfma_f32_16x16x32_bf16(a1, ldfrag(Bb + 32), acc[t], 0, 0, 0);
        }
        #pragma unroll
        for (int t = 0; t < 2; ++t) {
            int col = (w * 2 + t) * 16 + r16;
            float bb = b1[col];
            #pragma unroll
            for (int rr = 0; rr < 4; ++rr) {
                int e = crow + rr;
                float sp, sg;
                sp_sig(acc[t][rr] + bb, sp, sg);
                z1s[e * 136 + col] = f2bf(sp);
                S1g[(e0 + e) * 128 + col] = f2bf(sg);
            }
        }
    }
    __syncthreads();

    // stage W2s (2048 uint4)
    #pragma unroll
    for (int q = 0; q < 8; ++q) {
        int idx = q * 256 + tid;
        int row = idx >> 4, u4 = idx & 15;
        cpu4(&w2s[row * 136 + u4 * 8], &wsb[W2B_OFF + row * 128 + u4 * 8]);
    }
    __syncthreads();

    // fwd2: M=16 N=128 K=128 -> z2s (LDS overlay of z1s), S2g.
    // RACE FIX: hold all z1s A-fragments in registers, barrier, THEN mfma+write.
    {
        const unsigned short* Ab = z1s + r16 * 136 + kb * 8;
        bf16x8 a[4];
        #pragma unroll
        for (int ks = 0; ks < 4; ++ks) a[ks] = ldfrag(Ab + ks * 32);
        __syncthreads();   // every wave's z1s reads complete before any z2s write
        f32x4 acc[2] = {};
        #pragma unroll
        for (int t = 0; t < 2; ++t) {
            int col16 = (w * 2 + t) * 16 + r16;
            const unsigned short* Bb = w2s + col16 * 136 + kb * 8;
            #pragma unroll
            for (int ks = 0; ks < 4; ++ks)
                acc[t] = __builtin_amdgcn_mfma_f32_16x16x32_bf16(a[ks], ldfrag(Bb + ks * 32), acc[t], 0, 0, 0);
        }
        #pragma unroll
        for (int t = 0; t < 2; ++t) {
            int col = (w * 2 + t) * 16 + r16;
            float bb = b2[col];
            #pragma unroll
            for (int rr = 0; rr < 4; ++rr) {
                int e = crow + rr;
                float sp, sg;
                sp_sig(acc[t][rr] + bb, sp, sg);
                z2s[e * 136 + col] = f2bf(sp);
                S2g[(e0 + e) * 128 + col] = f2bf(sg);
            }
        }
    }

    // fwd3: 4 chunks of 128 cols; wc overlays w2s
    for (int nc = 0; nc < 4; ++nc) {
        __syncthreads();   // z2s writes + prior-chunk readers done before restaging wc
        #pragma unroll
        for (int q = 0; q < 8; ++q) {
            int idx = q * 256 + tid;
            int row = idx >> 4, u4 = idx & 15;
            cpu4(&wc[row * 136 + u4 * 8], &wsb[W3B_OFF + (nc * 128 + row) * 128 + u4 * 8]);
        }
        __syncthreads();

        const unsigned short* Ab = z2s + r16 * 136 + kb * 8;
        bf16x8 a[4];
        #pragma unroll
        for (int ks = 0; ks < 4; ++ks) a[ks] = ldfrag(Ab + ks * 32);
        f32x4 acc[2] = {};
        #pragma unroll
        for (int t = 0; t < 2; ++t) {
            int col16 = (w * 2 + t) * 16 + r16;
            const unsigned short* Bb = wc + col16 * 136 + kb * 8;
            #pragma unroll
            for (int ks = 0; ks < 4; ++ks)
                acc[t] = __builtin_amdgcn_mfma_f32_16x16x32_bf16(a[ks], ldfrag(Bb + ks * 32), acc[t], 0, 0, 0);
        }
        #pragma unroll
        for (int t = 0; t < 2; ++t) {
            int c = nc * 128 + (w * 2 + t) * 16 + r16;
            float bb = b3[c];
            #pragma unroll
            for (int rr = 0; rr < 4; ++rr) {
                int e = crow + rr;
                float v = tanh_fast(acc[t][rr] + bb);
                Vg[(e0 + e) * 512 + c] = f2bf(v);
            }
        }
    }
}

// ============ K3: T-build + jvp1 + jvp2 (dZ1 stays in LDS) ============
// 8 elems/block, grid 2048, 3 blocks/CU (53376 B).
// Phase A: vs[8][520]@0 | w1s[128][72]@8320 | ts[64][72]@26752
// Phase B: dz1s[64][136]@0 | w2s[128][136]@17408   sigs f32[288]@52224
#define K3_LDS 53376
__global__ __launch_bounds__(256, 3)
void k3_jvp12(const float* __restrict__ sigg,
              unsigned short* __restrict__ wsb) {
    __shared__ __align__(16) char sm[K3_LDS];
    unsigned short* vs   = (unsigned short*)(sm);           // [8][520]
    unsigned short* w1s  = (unsigned short*)(sm + 8320);    // [128][72]
    unsigned short* ts   = (unsigned short*)(sm + 26752);   // [64][72]
    unsigned short* dz1s = (unsigned short*)(sm);           // [64][136] phase B
    unsigned short* w2s  = (unsigned short*)(sm + 17408);   // [128][136] phase B
    float* sigsm = (float*)(sm + 52224);                    // [288]
    const unsigned short* S1g = wsb + S1_OFF;
    const unsigned short* S2g = wsb + S2_OFF;
    const unsigned short* Vg  = wsb + V_OFF;
    unsigned short* DZ2g = wsb + DZ2_OFF;

    const int tid = threadIdx.x;
    const int e0 = blockIdx.x * 8;
    const int lane = tid & 63;
    const int w = tid >> 6;
    const int r16 = lane & 15;
    const int kb = lane >> 4;

    #pragma unroll
    for (int q = 0; q < 2; ++q) {
        int idx = q * 256 + tid;               // 0..511
        int row = idx >> 6, u4 = idx & 63;
        cpu4(&vs[row * 520 + u4 * 8], &Vg[(e0 + row) * 512 + u4 * 8]);
    }
    #pragma unroll
    for (int q = 0; q < 4; ++q) {
        int idx = q * 256 + tid;
        int row = idx >> 3, u4 = idx & 7;
        cpu4(&w1s[row * 72 + u4 * 8], &wsb[W1B_OFF + row * 64 + u4 * 8]);
    }
    #pragma unroll
    for (int q = 0; q < 2; ++q) {
        int idx = q * 256 + tid;
        if (idx < 288) sigsm[idx] = sigg[e0 * 36 + idx];
    }
    __syncthreads();

    // T-build: T[m=e*8+j][k] = sum_i c[i][j]_e * V[e][i*64+k]
    {
        int m = tid >> 2, kq = tid & 3;
        int e = m >> 3, j = m & 7;
        float c8[8];
        #pragma unroll
        for (int i = 0; i < 8; ++i) {
            float v = 0.f;
            if (i < j) {
                int p = 7 * i - i * (i - 1) / 2 + (j - i - 1);
                v = sigsm[e * 36 + 8 + p];
            } else if (i > j) {
                int p = 7 * j - j * (j - 1) / 2 + (i - j - 1);
                v = -sigsm[e * 36 + 8 + p];
            }
            c8[i] = v;
        }
        float acc[16] = {};
        #pragma unroll
        for (int i = 0; i < 8; ++i) {
            uint4 qa = *reinterpret_cast<const uint4*>(&vs[e * 520 + i * 64 + kq * 16]);
            uint4 qb = *reinterpret_cast<const uint4*>(&vs[e * 520 + i * 64 + kq * 16 + 8]);
            float fa[8], fb[8];
            unpack8(qa, fa); unpack8(qb, fb);
            #pragma unroll
            for (int kk = 0; kk < 8; ++kk) {
                acc[kk]     += c8[i] * fa[kk];
                acc[kk + 8] += c8[i] * fb[kk];
            }
        }
        unsigned short o[16];
        #pragma unroll
        for (int kk = 0; kk < 16; ++kk) o[kk] = f2bf(acc[kk]);
        uint4 qo;
        qo.x = (unsigned int)o[0] | ((unsigned int)o[1] << 16);
        qo.y = (unsigned int)o[2] | ((unsigned int)o[3] << 16);
        qo.z = (unsigned int)o[4] | ((unsigned int)o[5] << 16);
        qo.w = (unsigned int)o[6] | ((unsigned int)o[7] << 16);
        *reinterpret_cast<uint4*>(&ts[m * 72 + kq * 16]) = qo;
        qo.x = (unsigned int)o[8]  | ((unsigned int)o[9]  << 16);
        qo.y = (unsigned int)o[10] | ((unsigned int)o[11] << 16);
        qo.z = (unsigned int)o[12] | ((unsigned int)o[13] << 16);
        qo.w = (unsigned int)o[14] | ((unsigned int)o[15] << 16);
        *reinterpret_cast<uint4*>(&ts[m * 72 + kq * 16 + 8]) = qo;
    }
    __syncthreads();

    // jvp1: masked (T @ W1^T) held in registers   M=64 N=128 K=64
    float dz1v[8][4];
    const int rbase = w * 16 + kb * 4;
    const int e_loc = rbase >> 3;               // rbase&7 in {0,4} -> constant over rr
    {
        const unsigned short* Ab = ts + (w * 16 + r16) * 72 + kb * 8;
        bf16x8 a0 = ldfrag(Ab), a1 = ldfrag(Ab + 32);
        f32x4 acc[8] = {};
        #pragma unroll
        for (int nt = 0; nt < 8; ++nt) {
            const unsigned short* Bb = w1s + (nt * 16 + r16) * 72 + kb * 8;
            acc[nt] = __builtin_amdgcn_mfma_f32_16x16x32_bf16(a0, ldfrag(Bb), acc[nt], 0, 0, 0);
            acc[nt] = __builtin_amdgcn_mfma_f32_16x16x32_bf16(a1, ldfrag(Bb + 32), acc[nt], 0, 0, 0);
        }
        #pragma unroll
        for (int nt = 0; nt < 8; ++nt) {
            int col = nt * 16 + r16;
            float s1v = bf2f(S1g[(e0 + e_loc) * 128 + col]);
            #pragma unroll
            for (int rr = 0; rr < 4; ++rr)
                dz1v[nt][rr] = acc[nt][rr] * s1v;
        }
    }
    __syncthreads();   // all reads of ts/w1s/vs complete before overlay writes

    // write dz1s (overlay vs/w1s head) + stage w2s (overlay w1s tail/ts)
    #pragma unroll
    for (int nt = 0; nt < 8; ++nt) {
        int col = nt * 16 + r16;
        #pragma unroll
        for (int rr = 0; rr < 4; ++rr)
            dz1s[(rbase + rr) * 136 + col] = f2bf(dz1v[nt][rr]);
    }
    #pragma unroll
    for (int q = 0; q < 8; ++q) {
        int idx = q * 256 + tid;
        int row = idx >> 4, u4 = idx & 15;
        cpu4(&w2s[row * 136 + u4 * 8], &wsb[W2B_OFF + row * 128 + u4 * 8]);
    }
    __syncthreads();

    // jvp2: dZ2 = (dZ1 @ W2^T) .* s2 -> global   M=64 N=128 K=128
    {
        const unsigned short* Ab = dz1s + (w * 16 + r16) * 136 + kb * 8;
        bf16x8 a[4];
        #pragma unroll
        for (int ks = 0; ks < 4; ++ks) a[ks] = ldfrag(Ab + ks * 32);
        f32x4 acc[8] = {};
        #pragma unroll
        for (int nt = 0; nt < 8; ++nt) {
            const unsigned short* Bb = w2s + (nt * 16 + r16) * 136 + kb * 8;
            #pragma unroll
            for (int ks = 0; ks < 4; ++ks)
                acc[nt] = __builtin_amdgcn_mfma_f32_16x16x32_bf16(a[ks], ldfrag(Bb + ks * 32), acc[nt], 0, 0, 0);
        }
        #pragma unroll
        for (int nt = 0; nt < 8; ++nt) {
            int col = nt * 16 + r16;
            float s2v = bf2f(S2g[(e0 + e_loc) * 128 + col]);
            #pragma unroll
            for (int rr = 0; rr < 4; ++rr)
                DZ2g[(e0 * 8 + rbase + rr) * 128 + col] = f2bf(acc[nt][rr] * s2v);
        }
    }
}

// ============ K4: jvp3 + mask + level-1; A direct from global, W3j double-buffered ============
// 16 elems/block, grid 1024, 4 blocks/CU.
// LDS: w3j[2][64][136]@0 (34816) + sg1[16][9]f32@34816 (576) = 35392
#define K4_LDS 35392
__global__ __launch_bounds__(256, 4)
void k4_jvp3(const float* __restrict__ sigg,
             const unsigned short* __restrict__ wsb,
             float* __restrict__ out) {
    __shared__ __align__(16) char sm[K4_LDS];
    unsigned short* w3j0 = (unsigned short*)(sm);            // [64][136]
    unsigned short* w3j1 = (unsigned short*)(sm + 17408);    // [64][136]
    float*          sg1  = (float*)(sm + 34816);             // [16][9]
    const unsigned short* Vg = wsb + V_OFF;
    const unsigned short* DZ2g = wsb + DZ2_OFF;

    const int tid = threadIdx.x;
    const int e0 = blockIdx.x * 16;
    const int lane = tid & 63;
    const int w = tid >> 6;            // wave w -> n-tile w
    const int r16 = lane & 15;
    const int kb = lane >> 4;
    const int crow = kb * 4;
    const int np = w * 16 + r16;

    if (tid < 128) {
        int e = tid >> 3, j7 = tid & 7;
        sg1[e * 9 + j7] = sigg[(e0 + e) * 36 + j7];
    }
    // stage w3j(0) into buf0
    #pragma unroll
    for (int q = 0; q < 4; ++q) {
        int idx = q * 256 + tid;
        int row = idx >> 4, u4 = idx & 15;
        cpu4(&w3j0[row * 136 + u4 * 8], &wsb[W3B_OFF + row * 128 + u4 * 8]);
    }
    __syncthreads();

    float oacc[4] = {};
    const unsigned short* Agbase = DZ2g + (e0 + r16) * 8 * 128 + kb * 8;

    for (int j = 0; j < 8; ++j) {
        unsigned short* cur = (j & 1) ? w3j1 : w3j0;
        unsigned short* nxt = (j & 1) ? w3j0 : w3j1;
        if (j < 7) {
            #pragma unroll
            for (int q = 0; q < 4; ++q) {
                int idx = q * 256 + tid;
                int row = idx >> 4, u4 = idx & 15;
                cpu4(&nxt[row * 136 + u4 * 8], &wsb[W3B_OFF + ((j + 1) * 64 + row) * 128 + u4 * 8]);
            }
        }
        const unsigned short* Ag = Agbase + j * 128;
        bf16x8 a[4];
        #pragma unroll
        for (int ks = 0; ks < 4; ++ks) a[ks] = ldfrag(Ag + ks * 32);
        f32x4 acc = {};
        const unsigned short* Bb = cur + np * 136 + kb * 8;
        #pragma unroll
        for (int ks = 0; ks < 4; ++ks)
            acc = __builtin_amdgcn_mfma_f32_16x16x32_bf16(a[ks], ldfrag(Bb + ks * 32), acc, 0, 0, 0);

        #pragma unroll
        for (int rr = 0; rr < 4; ++rr) {
            int e = crow + rr;
            float v = bf2f(Vg[(e0 + e) * 512 + j * 64 + np]);
            float sv = sg1[e * 9 + j];
            oacc[rr] += sv * v + (1.f - v * v) * acc[rr];
        }
        __syncthreads();   // cur fully read by all waves before being restaged at j+1
    }

    #pragma unroll
    for (int rr = 0; rr < 4; ++rr)
        out[(e0 + crow + rr) * 64 + np] = oacc[rr];
}

extern "C" void kernel_launch(void* const* d_in, const int* in_sizes, int n_in,
                              void* d_out, int out_size, void* d_ws, size_t ws_size,
                              hipStream_t stream) {
    const float* hg  = (const float*)d_in[0];
    const float* sg  = (const float*)d_in[1];
    const float* W1  = (const float*)d_in[2];
    const float* b1  = (const float*)d_in[3];
    const float* W2  = (const float*)d_in[4];
    const float* b2  = (const float*)d_in[5];
    const float* W3  = (const float*)d_in[6];
    const float* b3  = (const float*)d_in[7];
    float* outp = (float*)d_out;
    unsigned short* wsb = (unsigned short*)d_ws;

    hipLaunchKernelGGL(prep_weights, dim3((WS_WEIGHTS + 255) / 256), dim3(256), 0, stream,
                       W1, W2, W3, wsb);
    hipLaunchKernelGGL(k12_fwd, dim3(NEL / 16), dim3(256), 0, stream, hg, b1, b2, b3, wsb);
    hipLaunchKernelGGL(k3_jvp12, dim3(NEL / 8), dim3(256), 0, stream, sg, wsb);
    hipLaunchKernelGGL(k4_jvp3, dim3(NEL / 16), dim3(256), 0, stream, sg, wsb, outp);
}